// Round 1
// baseline (1095.293 us; speedup 1.0000x reference)
//
#include <hip/hip_runtime.h>

#define M_MAX 1024

__global__ __launch_bounds__(256) void init_out_kernel(
    const float* __restrict__ g, const float* __restrict__ s, const float* __restrict__ v,
    float* __restrict__ out) {
  const int NG = 4096 * 256, NS = 4096 * 256;
  int i = blockIdx.x * 256 + threadIdx.x;
  if (i < NG) out[i] = g[i];
  else if (i < NG + NS) out[i] = s[i - NG];
  else out[i] = v[i - NG - NS];
}

// One block per query. Finds k-nearest-within-radius for both scales,
// max-pools relu(rel@W1 + b1), then computes the 256-wide W2 row-GEMM
// and accumulates into out[q].
__global__ __launch_bounds__(256) void bq_stack_kernel(
    const float* __restrict__ qpts,
    const float* __restrict__ ppts, int Np,
    const float* __restrict__ W1,   // [2,3,128] for this stack
    const float* __restrict__ b1,   // [2,128]
    const float* __restrict__ W2,   // [256,256]
    const float* __restrict__ b2,   // [256]
    float* __restrict__ out) {      // [Nq,256] region for this query set
  __shared__ unsigned long long keys[M_MAX];
  __shared__ float f_lds[256];
  __shared__ int cnt_s;
  __shared__ float qsh[3];

  const int tid = threadIdx.x;
  const int q = blockIdx.x;

  if (tid == 0) {
    cnt_s = 0;
    qsh[0] = qpts[q * 3 + 0];
    qsh[1] = qpts[q * 3 + 1];
    qsh[2] = qpts[q * 3 + 2];
  }
  __syncthreads();
  const float qx = qsh[0], qy = qsh[1], qz = qsh[2];

  // Collect candidates within the larger radius (r=0.2, r^2=0.04).
  for (int p = tid; p < Np; p += 256) {
    float dx = ppts[p * 3 + 0] - qx;
    float dy = ppts[p * 3 + 1] - qy;
    float dz = ppts[p * 3 + 2] - qz;
    float d2 = dx * dx + dy * dy + dz * dz;
    if (d2 <= 0.04f) {
      int pos = atomicAdd(&cnt_s, 1);
      if (pos < M_MAX) {
        keys[pos] = ((unsigned long long)__float_as_uint(d2) << 32) | (unsigned int)p;
      }
    }
  }
  __syncthreads();
  const int cnt = min(cnt_s, M_MAX);
  for (int i = cnt + tid; i < M_MAX; i += 256) keys[i] = ~0ULL;
  __syncthreads();

  // Bitonic sort ascending (d2 major, point index minor — matches top_k ties).
  for (int size = 2; size <= M_MAX; size <<= 1) {
    for (int stride = size >> 1; stride > 0; stride >>= 1) {
#pragma unroll
      for (int w = 0; w < M_MAX / 256; ++w) {
        int i = w * 256 + tid;
        int j = i ^ stride;
        if (j > i) {
          unsigned long long a = keys[i], b = keys[j];
          bool asc = ((i & size) == 0);
          if ((a > b) == asc) { keys[i] = b; keys[j] = a; }
        }
      }
      __syncthreads();
    }
  }

  // Max-pool: threads [0,128) = scale 0 (k=16, r2=0.01), [128,256) = scale 1 (k=32, r2=0.04).
  {
    const int scale = tid >> 7;
    const int h = tid & 127;
    const int K = scale ? 32 : 16;
    const unsigned int rlim = __float_as_uint(scale ? 0.04f : 0.01f);
    const float w0 = W1[(scale * 3 + 0) * 128 + h];
    const float w1 = W1[(scale * 3 + 1) * 128 + h];
    const float w2 = W1[(scale * 3 + 2) * 128 + h];
    const float bb = b1[scale * 128 + h];
    float maxv = -INFINITY;
    const int lim = min(K, cnt);
    for (int j = 0; j < lim; ++j) {
      unsigned long long key = keys[j];
      unsigned int d2b = (unsigned int)(key >> 32);
      if (d2b > rlim) break;   // sorted: no later candidate can be valid
      int idx = (int)(key & 0xffffffffu);
      float rx = ppts[idx * 3 + 0] - qx;
      float ry = ppts[idx * 3 + 1] - qy;
      float rz = ppts[idx * 3 + 2] - qz;
      float val = rx * w0 + ry * w1 + rz * w2;
      maxv = fmaxf(maxv, val);
    }
    // empty set: maxv = -inf -> relu gives 0 (matches reference's where(isfinite,...,0))
    f_lds[tid] = fmaxf(maxv + bb, 0.0f);
  }
  __syncthreads();

  // W2 row-GEMM: out[q, tid] += f @ W2[:, tid] + b2[tid]
  float acc = b2[tid];
  for (int f = 0; f < 256; ++f) {
    acc += f_lds[f] * W2[f * 256 + tid];
  }
  out[q * 256 + tid] += acc;
}

extern "C" void kernel_launch(void* const* d_in, const int* in_sizes, int n_in,
                              void* d_out, int out_size, void* d_ws, size_t ws_size,
                              hipStream_t stream) {
  const float* g      = (const float*)d_in[0];
  const float* s      = (const float*)d_in[1];
  const float* v      = (const float*)d_in[2];
  const float* geo_t  = (const float*)d_in[3];
  const float* surf_t = (const float*)d_in[4];
  const float* vol_t  = (const float*)d_in[5];
  const float* W1     = (const float*)d_in[6];
  const float* b1     = (const float*)d_in[7];
  const float* W2     = (const float*)d_in[8];
  const float* b2     = (const float*)d_in[9];
  float* out = (float*)d_out;

  const int NG = 4096, NS = 4096, NV = 8192;
  float* out_g = out;
  float* out_s = out + NG * 256;
  float* out_v = out + (NG + NS) * 256;

  const int total = (NG + NS + NV) * 256;
  hipLaunchKernelGGL(init_out_kernel, dim3(total / 256), dim3(256), 0, stream,
                     geo_t, surf_t, vol_t, out);

  auto launch = [&](int stack, const float* qp, int Nq, const float* pp, int Np, float* o) {
    hipLaunchKernelGGL(bq_stack_kernel, dim3(Nq), dim3(256), 0, stream,
                       qp, pp, Np,
                       W1 + stack * 2 * 3 * 128,
                       b1 + stack * 2 * 128,
                       W2 + stack * 256 * 256,
                       b2 + stack * 256,
                       o);
  };

  // geo_tokens += stacks 0 (g,g), 3 (g,s), 4 (g,v)
  launch(0, g, NG, g, NG, out_g);
  launch(3, g, NG, s, NS, out_g);
  launch(4, g, NG, v, NV, out_g);
  // surf_tokens += stacks 1 (s,s), 5 (s,g)
  launch(1, s, NS, s, NS, out_s);
  launch(5, s, NS, g, NG, out_s);
  // vol_tokens += stacks 2 (v,v), 6 (v,g)
  launch(2, v, NV, v, NV, out_v);
  launch(6, v, NV, g, NG, out_v);
}

// Round 2
// 583.788 us; speedup vs baseline: 1.8762x; 1.8762x over previous
//
#include <hip/hip_runtime.h>

#define M_MAX 1024
#define TMP_CAP 128

__global__ __launch_bounds__(256) void init_out_kernel(
    const float* __restrict__ g, const float* __restrict__ s, const float* __restrict__ v,
    float* __restrict__ out) {
  const int NG = 4096 * 256, NS = 4096 * 256;
  int i = blockIdx.x * 256 + threadIdx.x;
  if (i < NG) out[i] = g[i];
  else if (i < NG + NS) out[i] = s[i - NG];
  else out[i] = v[i - NG - NS];
}

// One block per query. Histogram-select the k-nearest-within-radius sets
// (no full sort: selection feeds a max-pool, so only the SET matters; key =
// d2bits<<32|idx gives unique keys with top_k-compatible index tie-break),
// max-pool relu(rel@W1+b1), then split-K W2 row-GEMM accumulated into out.
__global__ __launch_bounds__(256) void bq_stack_kernel(
    const float* __restrict__ qpts,
    const float* __restrict__ ppts, int Np,
    const float* __restrict__ W1,   // [2,3,128]
    const float* __restrict__ b1,   // [2,128]
    const float* __restrict__ W2,   // [256,256]
    const float* __restrict__ b2,   // [256]
    float* __restrict__ out) {
  __shared__ unsigned long long keys[M_MAX];       // 8 KB; reused as GEMM scratch
  __shared__ int hist32[256];
  __shared__ int hist16[64];
  __shared__ unsigned long long tmpb[2][TMP_CAP];  // boundary-bin keys
  __shared__ int tmpcnt[2];
  __shared__ float4 sel[32];                       // relx,rely,relz, scale0-flag
  __shared__ int selcnt;
  __shared__ float f_lds[256];
  __shared__ int cnt_s;
  __shared__ unsigned long long T_lds[2];          // [0]=T16, [1]=T32
  __shared__ int bbin[2], msel[2];
  __shared__ int wsum[4];
  __shared__ float qsh[3];

  const int tid = threadIdx.x;
  const int lane = tid & 63;
  const int wv = tid >> 6;
  const int q = blockIdx.x;

  // ---- Phase A: init ----
  hist32[tid] = 0;
  if (tid < 64) hist16[tid] = 0;
  if (tid == 0) {
    cnt_s = 0; selcnt = 0; tmpcnt[0] = 0; tmpcnt[1] = 0;
    T_lds[0] = ~0ULL; T_lds[1] = ~0ULL;
    qsh[0] = qpts[q * 3 + 0]; qsh[1] = qpts[q * 3 + 1]; qsh[2] = qpts[q * 3 + 2];
  }
  __syncthreads();
  const float qx = qsh[0], qy = qsh[1], qz = qsh[2];

  // ---- Phase B: distance scan (4 pts/thread via float4), collect + histogram ----
  const float4* pp4 = (const float4*)ppts;
  const int groups = Np >> 2;
  for (int gp = tid; gp < groups; gp += 256) {
    float4 A = pp4[gp * 3 + 0];
    float4 Bv = pp4[gp * 3 + 1];
    float4 C = pp4[gp * 3 + 2];
    float px[4] = {A.x, A.w, Bv.z, C.y};
    float py[4] = {A.y, Bv.x, Bv.w, C.z};
    float pz[4] = {A.z, Bv.y, C.x, C.w};
#pragma unroll
    for (int t = 0; t < 4; ++t) {
      float dx = px[t] - qx, dy = py[t] - qy, dz = pz[t] - qz;
      float d2 = dx * dx + dy * dy + dz * dz;
      if (d2 <= 0.04f) {
        int pos = atomicAdd(&cnt_s, 1);
        if (pos < M_MAX)
          keys[pos] = ((unsigned long long)__float_as_uint(d2) << 32) | (unsigned)(gp * 4 + t);
        int b = min((int)(d2 * 6400.0f), 255);
        atomicAdd(&hist32[b], 1);
        if (d2 <= 0.01f) atomicAdd(&hist16[min(b, 63)], 1);
      }
    }
  }
  __syncthreads();
  const int cnt = min(cnt_s, M_MAX);

  // ---- Phase C: inclusive prefix scans (shuffle scan + cross-wave offsets) ----
  {
    int v = hist32[tid];
#pragma unroll
    for (int o = 1; o < 64; o <<= 1) {
      int t = __shfl_up(v, o, 64);
      if (lane >= o) v += t;
    }
    if (lane == 63) wsum[wv] = v;
    int v16 = 0;
    if (wv == 0) {
      v16 = hist16[lane];
#pragma unroll
      for (int o = 1; o < 64; o <<= 1) {
        int t = __shfl_up(v16, o, 64);
        if (lane >= o) v16 += t;
      }
    }
    __syncthreads();
    int off = 0;
    for (int w = 0; w < wv; ++w) off += wsum[w];
    hist32[tid] = v + off;
    if (wv == 0) hist16[lane] = v16;
    __syncthreads();
  }

  const int k32 = min(32, cnt);
  const int c16tot = hist16[63];
  const int k16 = min(16, c16tot);

  // ---- Phase D: find boundary bins ----
  {
    int c = hist32[tid], cp = tid ? hist32[tid - 1] : 0;
    if (k32 > 0 && c >= k32 && cp < k32) { bbin[1] = tid; msel[1] = k32 - cp; }
    if (tid < 64) {
      int c6 = hist16[tid], cp6 = tid ? hist16[tid - 1] : 0;
      if (k16 > 0 && c6 >= k16 && cp6 < k16) { bbin[0] = tid; msel[0] = k16 - cp6; }
    }
  }
  __syncthreads();

  // ---- Phase E: collect boundary-bin keys ----
  const int b32b = (k32 > 0) ? bbin[1] : -1;
  const int b16b = (k16 > 0) ? bbin[0] : -1;
  for (int i = tid; i < cnt; i += 256) {
    unsigned long long key = keys[i];
    float d2 = __uint_as_float((unsigned)(key >> 32));
    int b = min((int)(d2 * 6400.0f), 255);
    if (b == b32b) { int p = atomicAdd(&tmpcnt[1], 1); if (p < TMP_CAP) tmpb[1][p] = key; }
    if (d2 <= 0.01f && min(b, 63) == b16b) {
      int p = atomicAdd(&tmpcnt[0], 1); if (p < TMP_CAP) tmpb[0][p] = key;
    }
  }
  __syncthreads();

  // ---- Phase F: per-scale threshold key (wave 0 -> scale1, wave 1 -> scale0) ----
  if (wv < 2) {
    const int s = 1 - wv;
    const int k = s ? k32 : k16;
    if (k > 0) {
      const int h = min(tmpcnt[s], TMP_CAP);
      const int m = msel[s];
      if (h <= 64) {
        unsigned long long key = (lane < h) ? tmpb[s][lane] : ~0ULL;
#pragma unroll
        for (int kk = 2; kk <= 64; kk <<= 1) {
#pragma unroll
          for (int j = kk >> 1; j > 0; j >>= 1) {
            unsigned long long part = __shfl_xor(key, j, 64);
            bool keep_min = ((lane & j) == 0) == ((lane & kk) == 0);
            bool pgt = part > key;
            key = (keep_min == pgt) ? key : part;
          }
        }
        if (lane == m - 1) T_lds[s] = key;
      } else {
        // rare generic path: rank-select among h <= TMP_CAP keys
        for (int i = lane; i < h; i += 64) {
          unsigned long long e = tmpb[s][i];
          int less = 0;
          for (int j = 0; j < h; ++j) less += (tmpb[s][j] < e);
          if (less == m - 1) T_lds[s] = e;
        }
      }
    }
  }
  __syncthreads();

  // ---- Phase G: compact selected neighbors (exactly k32, set16 subset flagged) ----
  {
    const unsigned long long T32 = T_lds[1], T16 = T_lds[0];
    for (int i = tid; i < cnt; i += 256) {
      unsigned long long key = keys[i];
      if (key <= T32) {
        float d2 = __uint_as_float((unsigned)(key >> 32));
        int idx = (int)(key & 0xffffffffu);
        float rx = ppts[idx * 3 + 0] - qx;
        float ry = ppts[idx * 3 + 1] - qy;
        float rz = ppts[idx * 3 + 2] - qz;
        bool f16 = (k16 > 0) && (d2 <= 0.01f) && (key <= T16);
        int slot = atomicAdd(&selcnt, 1);
        if (slot < 32) sel[slot] = make_float4(rx, ry, rz, f16 ? 1.0f : 0.0f);
      }
    }
  }
  __syncthreads();

  // ---- Phase H: masked max-pool -> f ----
  {
    const int nsel = min(selcnt, 32);
    const int scale = tid >> 7;
    const int h = tid & 127;
    const float w0 = W1[(scale * 3 + 0) * 128 + h];
    const float w1 = W1[(scale * 3 + 1) * 128 + h];
    const float w2 = W1[(scale * 3 + 2) * 128 + h];
    const float bb = b1[scale * 128 + h];
    float maxv = -INFINITY;
    for (int j = 0; j < nsel; ++j) {
      float4 e = sel[j];
      float val = e.x * w0 + e.y * w1 + e.z * w2;
      bool ok = scale ? true : (e.w > 0.0f);
      maxv = ok ? fmaxf(maxv, val) : maxv;
    }
    f_lds[tid] = fmaxf(maxv + bb, 0.0f);  // -inf + b -> relu -> 0 (empty set)
  }
  __syncthreads();

  // ---- Phase I: W2 GEMM, 4-way split-K, float4 loads ----
  float* part = (float*)keys;  // reuse 8KB scratch (4KB used)
  {
    const int g4 = wv;            // K-group = wave
    float4 acc = make_float4(0.f, 0.f, 0.f, 0.f);
    for (int r = 0; r < 64; ++r) {
      float fv = f_lds[g4 * 64 + r];
      float4 w = ((const float4*)W2)[(g4 * 64 + r) * 64 + lane];
      acc.x += fv * w.x; acc.y += fv * w.y; acc.z += fv * w.z; acc.w += fv * w.w;
    }
    ((float4*)part)[g4 * 64 + lane] = acc;  // part[g4][lane*4 .. +3]
  }
  __syncthreads();
  {
    float sum = part[0 * 256 + tid] + part[1 * 256 + tid] + part[2 * 256 + tid] +
                part[3 * 256 + tid] + b2[tid];
    out[q * 256 + tid] += sum;
  }
}

extern "C" void kernel_launch(void* const* d_in, const int* in_sizes, int n_in,
                              void* d_out, int out_size, void* d_ws, size_t ws_size,
                              hipStream_t stream) {
  const float* g      = (const float*)d_in[0];
  const float* s      = (const float*)d_in[1];
  const float* v      = (const float*)d_in[2];
  const float* geo_t  = (const float*)d_in[3];
  const float* surf_t = (const float*)d_in[4];
  const float* vol_t  = (const float*)d_in[5];
  const float* W1     = (const float*)d_in[6];
  const float* b1     = (const float*)d_in[7];
  const float* W2     = (const float*)d_in[8];
  const float* b2     = (const float*)d_in[9];
  float* out = (float*)d_out;

  const int NG = 4096, NS = 4096, NV = 8192;
  float* out_g = out;
  float* out_s = out + NG * 256;
  float* out_v = out + (NG + NS) * 256;

  const int total = (NG + NS + NV) * 256;
  hipLaunchKernelGGL(init_out_kernel, dim3(total / 256), dim3(256), 0, stream,
                     geo_t, surf_t, vol_t, out);

  auto launch = [&](int stack, const float* qp, int Nq, const float* pp, int Np, float* o) {
    hipLaunchKernelGGL(bq_stack_kernel, dim3(Nq), dim3(256), 0, stream,
                       qp, pp, Np,
                       W1 + stack * 2 * 3 * 128,
                       b1 + stack * 2 * 128,
                       W2 + stack * 256 * 256,
                       b2 + stack * 256,
                       o);
  };

  launch(0, g, NG, g, NG, out_g);
  launch(3, g, NG, s, NS, out_g);
  launch(4, g, NG, v, NV, out_g);
  launch(1, s, NS, s, NS, out_s);
  launch(5, s, NS, g, NG, out_s);
  launch(2, v, NV, v, NV, out_v);
  launch(6, v, NV, g, NG, out_v);
}

// Round 4
// 513.401 us; speedup vs baseline: 2.1334x; 1.1371x over previous
//
#include <hip/hip_runtime.h>

#define CAND_CAP 512
#define TMP_CAP 96
#define M_MAX 1024
#define FTMP_CAP 128

__global__ __launch_bounds__(256) void init_out_kernel(
    const float* __restrict__ g, const float* __restrict__ s, const float* __restrict__ v,
    float* __restrict__ out) {
  const int NG = 4096 * 256, NS = 4096 * 256;
  int i = blockIdx.x * 256 + threadIdx.x;
  if (i < NG) out[i] = g[i];
  else if (i < NG + NS) out[i] = s[i - NG];
  else out[i] = v[i - NG - NS];
}

// ---------------- Kernel A: wave-per-query selection + max-pool ----------------
// 4 queries per block (one per wave). All LDS state is wave-private, so no
// __syncthreads; wave-lockstep + in-order DS pipe + fences give ordering.
__global__ __launch_bounds__(256) void bq_select_pool_kernel(
    const float* __restrict__ qpts,
    const float* __restrict__ ppts, int Np,
    const float* __restrict__ W1,   // [2,3,128]
    const float* __restrict__ b1,   // [2,128]
    float* __restrict__ fbuf) {     // [Nq,256]
  __shared__ unsigned long long keys[4][CAND_CAP];
  __shared__ unsigned long long tmpb[4][2][TMP_CAP];
  __shared__ unsigned long long Tkey[4][2];
  __shared__ int hist32[4][256];
  __shared__ int hist16[4][64];
  __shared__ int wcnt[4];
  __shared__ int scnt[4];
  __shared__ int tmpcnt[4][2];
  __shared__ int bbin[4][2];
  __shared__ int msel[4][2];
  __shared__ float4 sel[4][32];

  const int tid = threadIdx.x;
  const int lane = tid & 63;
  const int wv = tid >> 6;
  const int q = blockIdx.x * 4 + wv;

  // per-wave init
#pragma unroll
  for (int i = 0; i < 4; ++i) hist32[wv][lane + 64 * i] = 0;
  hist16[wv][lane] = 0;
  if (lane == 0) {
    wcnt[wv] = 0; scnt[wv] = 0;
    tmpcnt[wv][0] = 0; tmpcnt[wv][1] = 0;
    Tkey[wv][0] = 0; Tkey[wv][1] = 0;
    bbin[wv][0] = -1; bbin[wv][1] = -1;
    msel[wv][0] = 0; msel[wv][1] = 0;
  }
  const float qx = qpts[q * 3 + 0];
  const float qy = qpts[q * 3 + 1];
  const float qz = qpts[q * 3 + 2];
  __builtin_amdgcn_wave_barrier();
  __threadfence_block();

  // scan all points: 64 lanes x 4 points per iter, float4 loads
  const float4* pp4 = (const float4*)ppts;
  const int niter = Np >> 8;
  for (int it = 0; it < niter; ++it) {
    const int gp = it * 64 + lane;
    float4 A = pp4[gp * 3 + 0];
    float4 Bv = pp4[gp * 3 + 1];
    float4 C = pp4[gp * 3 + 2];
    float px[4] = {A.x, A.w, Bv.z, C.y};
    float py[4] = {A.y, Bv.x, Bv.w, C.z};
    float pz[4] = {A.z, Bv.y, C.x, C.w};
#pragma unroll
    for (int t = 0; t < 4; ++t) {
      float dx = px[t] - qx, dy = py[t] - qy, dz = pz[t] - qz;
      float d2 = dx * dx + dy * dy + dz * dz;
      if (d2 <= 0.04f) {
        int pos = atomicAdd(&wcnt[wv], 1);
        if (pos < CAND_CAP)
          keys[wv][pos] = ((unsigned long long)__float_as_uint(d2) << 32) | (unsigned)(gp * 4 + t);
        int b = min((int)(d2 * 6400.0f), 255);
        atomicAdd(&hist32[wv][b], 1);
        if (d2 <= 0.01f) atomicAdd(&hist16[wv][min(b, 63)], 1);
      }
    }
  }
  __builtin_amdgcn_wave_barrier();
  __threadfence_block();
  const int cnt = min(wcnt[wv], CAND_CAP);
  const int k32 = min(32, cnt);

  // prefix scan hist32 (lane owns 4 consecutive bins) + boundary bin for k32
  {
    int h0 = hist32[wv][lane * 4 + 0];
    int h1 = hist32[wv][lane * 4 + 1];
    int h2 = hist32[wv][lane * 4 + 2];
    int h3 = hist32[wv][lane * 4 + 3];
    int c1 = h0 + h1, c2 = c1 + h2, c3 = c2 + h3;
    int incl = c3;
#pragma unroll
    for (int o = 1; o < 64; o <<= 1) {
      int t = __shfl_up(incl, o, 64);
      if (lane >= o) incl += t;
    }
    int off = incl - c3;  // exclusive prefix of this lane's quad
    if (k32 > 0) {
      int cum0 = off + h0, cum1 = off + c1, cum2 = off + c2, cum3 = off + c3;
      if (cum0 >= k32 && off  < k32) { bbin[wv][1] = lane * 4 + 0; msel[wv][1] = k32 - off;  }
      if (cum1 >= k32 && cum0 < k32) { bbin[wv][1] = lane * 4 + 1; msel[wv][1] = k32 - cum0; }
      if (cum2 >= k32 && cum1 < k32) { bbin[wv][1] = lane * 4 + 2; msel[wv][1] = k32 - cum1; }
      if (cum3 >= k32 && cum2 < k32) { bbin[wv][1] = lane * 4 + 3; msel[wv][1] = k32 - cum2; }
    }
  }
  // hist16 scan + boundary bin for k16
  int k16;
  {
    int g = hist16[wv][lane];
    int incl = g;
#pragma unroll
    for (int o = 1; o < 64; o <<= 1) {
      int t = __shfl_up(incl, o, 64);
      if (lane >= o) incl += t;
    }
    int tot = __shfl(incl, 63, 64);
    k16 = min(16, tot);
    if (k16 > 0) {
      int prev = incl - g;
      if (incl >= k16 && prev < k16) { bbin[wv][0] = lane; msel[wv][0] = k16 - prev; }
    }
  }
  __builtin_amdgcn_wave_barrier();
  __threadfence_block();
  const int b32b = bbin[wv][1];
  const int b16b = bbin[wv][0];

  // collect boundary-bin keys
  for (int i = lane; i < cnt; i += 64) {
    unsigned long long key = keys[wv][i];
    float d2 = __uint_as_float((unsigned)(key >> 32));
    int b = min((int)(d2 * 6400.0f), 255);
    if (b == b32b) { int p = atomicAdd(&tmpcnt[wv][1], 1); if (p < TMP_CAP) tmpb[wv][1][p] = key; }
    if (d2 <= 0.01f && min(b, 63) == b16b) {
      int p = atomicAdd(&tmpcnt[wv][0], 1); if (p < TMP_CAP) tmpb[wv][0][p] = key;
    }
  }
  __builtin_amdgcn_wave_barrier();
  __threadfence_block();

  // rank-select the m-th smallest key in each boundary bin (h is tiny: ~1-3)
#pragma unroll
  for (int s = 0; s < 2; ++s) {
    const int k = s ? k32 : k16;
    if (k > 0) {
      const int h = min(tmpcnt[wv][s], TMP_CAP);
      const int m = msel[wv][s];
      for (int base = 0; base < h; base += 64) {
        int ii = base + lane;
        if (ii < h) {
          unsigned long long e = tmpb[wv][s][ii];
          int less = 0;
          for (int j = 0; j < h; ++j) less += (tmpb[wv][s][j] < e) ? 1 : 0;
          if (less == m - 1) Tkey[wv][s] = e;
        }
      }
    }
  }
  __builtin_amdgcn_wave_barrier();
  __threadfence_block();
  const unsigned long long T32 = Tkey[wv][1];
  const unsigned long long T16 = Tkey[wv][0];

  // compact selected neighbors (exactly k32 of them; scale-0 membership flagged)
  for (int i = lane; i < cnt; i += 64) {
    unsigned long long key = keys[wv][i];
    if (k32 > 0 && key <= T32) {
      float d2 = __uint_as_float((unsigned)(key >> 32));
      int idx = (int)(key & 0xffffffffu);
      float rx = ppts[idx * 3 + 0] - qx;
      float ry = ppts[idx * 3 + 1] - qy;
      float rz = ppts[idx * 3 + 2] - qz;
      bool f16 = (k16 > 0) && (d2 <= 0.01f) && (key <= T16);
      int slot = atomicAdd(&scnt[wv], 1);
      if (slot < 32) sel[wv][slot] = make_float4(rx, ry, rz, f16 ? 1.0f : 0.0f);
    }
  }
  __builtin_amdgcn_wave_barrier();
  __threadfence_block();
  const int nsel = min(scnt[wv], 32);

  // masked max-pool; lane covers channels lane*4..+3 (lanes<32: scale0, else scale1)
  {
    const int scale = lane >> 5;
    const int hbase = (lane & 31) * 4;
    const float4 wx = *(const float4*)(W1 + scale * 384 + 0 * 128 + hbase);
    const float4 wy = *(const float4*)(W1 + scale * 384 + 1 * 128 + hbase);
    const float4 wz = *(const float4*)(W1 + scale * 384 + 2 * 128 + hbase);
    const float4 bb = *(const float4*)(b1 + scale * 128 + hbase);
    float m0 = -INFINITY, m1 = -INFINITY, m2 = -INFINITY, m3 = -INFINITY;
    for (int n = 0; n < nsel; ++n) {
      float4 e = sel[wv][n];
      bool ok = scale ? true : (e.w > 0.5f);
      float v0 = e.x * wx.x + e.y * wy.x + e.z * wz.x;
      float v1 = e.x * wx.y + e.y * wy.y + e.z * wz.y;
      float v2 = e.x * wx.z + e.y * wy.z + e.z * wz.z;
      float v3 = e.x * wx.w + e.y * wy.w + e.z * wz.w;
      if (ok) { m0 = fmaxf(m0, v0); m1 = fmaxf(m1, v1); m2 = fmaxf(m2, v2); m3 = fmaxf(m3, v3); }
    }
    float4 f4 = make_float4(fmaxf(m0 + bb.x, 0.0f), fmaxf(m1 + bb.y, 0.0f),
                            fmaxf(m2 + bb.z, 0.0f), fmaxf(m3 + bb.w, 0.0f));
    *(float4*)(fbuf + q * 256 + lane * 4) = f4;
  }
}

// ---------------- Kernel B: out += f @ W2 + b2, 16 queries per block ----------------
#define FMA4(acc, s_, W_) { (acc).x += (s_) * (W_).x; (acc).y += (s_) * (W_).y; (acc).z += (s_) * (W_).z; (acc).w += (s_) * (W_).w; }

__global__ __launch_bounds__(256) void bq_gemm_kernel(
    const float* __restrict__ fbuf,   // [Nq,256]
    const float* __restrict__ W2,     // [256,256]
    const float* __restrict__ b2,     // [256]
    float* __restrict__ out) {
  __shared__ float ftile[16 * 256];
  const int tid = threadIdx.x;
  const int lane = tid & 63;
  const int wv = tid >> 6;
  const int qbase = blockIdx.x * 16;

  {
    const float4* src = (const float4*)(fbuf + qbase * 256);
    float4* dst = (float4*)ftile;
#pragma unroll
    for (int i = 0; i < 4; ++i) dst[tid + 256 * i] = src[tid + 256 * i];
  }
  __syncthreads();

  float4 acc0 = make_float4(0.f,0.f,0.f,0.f), acc1 = acc0, acc2 = acc0, acc3 = acc0;
  const float4* w24 = (const float4*)W2;
  const float* fb = ftile + wv * 4 * 256;

  for (int f = 0; f < 256; f += 4) {
    float4 fq0 = *(const float4*)(fb + 0 * 256 + f);
    float4 fq1 = *(const float4*)(fb + 1 * 256 + f);
    float4 fq2 = *(const float4*)(fb + 2 * 256 + f);
    float4 fq3 = *(const float4*)(fb + 3 * 256 + f);
    float4 w0 = w24[(f + 0) * 64 + lane];
    float4 w1 = w24[(f + 1) * 64 + lane];
    float4 w2 = w24[(f + 2) * 64 + lane];
    float4 w3 = w24[(f + 3) * 64 + lane];
    FMA4(acc0, fq0.x, w0) FMA4(acc0, fq0.y, w1) FMA4(acc0, fq0.z, w2) FMA4(acc0, fq0.w, w3)
    FMA4(acc1, fq1.x, w0) FMA4(acc1, fq1.y, w1) FMA4(acc1, fq1.z, w2) FMA4(acc1, fq1.w, w3)
    FMA4(acc2, fq2.x, w0) FMA4(acc2, fq2.y, w1) FMA4(acc2, fq2.z, w2) FMA4(acc2, fq2.w, w3)
    FMA4(acc3, fq3.x, w0) FMA4(acc3, fq3.y, w1) FMA4(acc3, fq3.z, w2) FMA4(acc3, fq3.w, w3)
  }

  const float4 bb = ((const float4*)b2)[lane];
  float4* out4 = (float4*)out;
#pragma unroll
  for (int j = 0; j < 4; ++j) {
    float4 a = (j == 0) ? acc0 : (j == 1) ? acc1 : (j == 2) ? acc2 : acc3;
    int q = qbase + wv * 4 + j;
    float4 o = out4[q * 64 + lane];
    o.x += a.x + bb.x; o.y += a.y + bb.y; o.z += a.z + bb.z; o.w += a.w + bb.w;
    out4[q * 64 + lane] = o;
  }
}

// ---------------- Fallback: round-2 fused kernel (used only if ws too small) ----------------
__global__ __launch_bounds__(256) void bq_stack_fused(
    const float* __restrict__ qpts,
    const float* __restrict__ ppts, int Np,
    const float* __restrict__ W1, const float* __restrict__ b1,
    const float* __restrict__ W2, const float* __restrict__ b2,
    float* __restrict__ out) {
  __shared__ unsigned long long keys[M_MAX];
  __shared__ int hist32[256];
  __shared__ int hist16[64];
  __shared__ unsigned long long tmpb[2][FTMP_CAP];
  __shared__ int tmpcnt[2];
  __shared__ float4 sel[32];
  __shared__ int selcnt;
  __shared__ float f_lds[256];
  __shared__ int cnt_s;
  __shared__ unsigned long long T_lds[2];
  __shared__ int bbin[2], msel[2];
  __shared__ int wsum[4];
  __shared__ float qsh[3];

  const int tid = threadIdx.x;
  const int lane = tid & 63;
  const int wv = tid >> 6;
  const int q = blockIdx.x;

  hist32[tid] = 0;
  if (tid < 64) hist16[tid] = 0;
  if (tid == 0) {
    cnt_s = 0; selcnt = 0; tmpcnt[0] = 0; tmpcnt[1] = 0;
    T_lds[0] = ~0ULL; T_lds[1] = ~0ULL;
    qsh[0] = qpts[q * 3 + 0]; qsh[1] = qpts[q * 3 + 1]; qsh[2] = qpts[q * 3 + 2];
  }
  __syncthreads();
  const float qx = qsh[0], qy = qsh[1], qz = qsh[2];

  const float4* pp4 = (const float4*)ppts;
  const int groups = Np >> 2;
  for (int gp = tid; gp < groups; gp += 256) {
    float4 A = pp4[gp * 3 + 0];
    float4 Bv = pp4[gp * 3 + 1];
    float4 C = pp4[gp * 3 + 2];
    float px[4] = {A.x, A.w, Bv.z, C.y};
    float py[4] = {A.y, Bv.x, Bv.w, C.z};
    float pz[4] = {A.z, Bv.y, C.x, C.w};
#pragma unroll
    for (int t = 0; t < 4; ++t) {
      float dx = px[t] - qx, dy = py[t] - qy, dz = pz[t] - qz;
      float d2 = dx * dx + dy * dy + dz * dz;
      if (d2 <= 0.04f) {
        int pos = atomicAdd(&cnt_s, 1);
        if (pos < M_MAX)
          keys[pos] = ((unsigned long long)__float_as_uint(d2) << 32) | (unsigned)(gp * 4 + t);
        int b = min((int)(d2 * 6400.0f), 255);
        atomicAdd(&hist32[b], 1);
        if (d2 <= 0.01f) atomicAdd(&hist16[min(b, 63)], 1);
      }
    }
  }
  __syncthreads();
  const int cnt = min(cnt_s, M_MAX);

  {
    int v = hist32[tid];
#pragma unroll
    for (int o = 1; o < 64; o <<= 1) {
      int t = __shfl_up(v, o, 64);
      if (lane >= o) v += t;
    }
    if (lane == 63) wsum[wv] = v;
    int v16 = 0;
    if (wv == 0) {
      v16 = hist16[lane];
#pragma unroll
      for (int o = 1; o < 64; o <<= 1) {
        int t = __shfl_up(v16, o, 64);
        if (lane >= o) v16 += t;
      }
    }
    __syncthreads();
    int off = 0;
    for (int w = 0; w < wv; ++w) off += wsum[w];
    hist32[tid] = v + off;
    if (wv == 0) hist16[lane] = v16;
    __syncthreads();
  }

  const int k32 = min(32, cnt);
  const int c16tot = hist16[63];
  const int k16 = min(16, c16tot);

  {
    int c = hist32[tid], cp = tid ? hist32[tid - 1] : 0;
    if (k32 > 0 && c >= k32 && cp < k32) { bbin[1] = tid; msel[1] = k32 - cp; }
    if (tid < 64) {
      int c6 = hist16[tid], cp6 = tid ? hist16[tid - 1] : 0;
      if (k16 > 0 && c6 >= k16 && cp6 < k16) { bbin[0] = tid; msel[0] = k16 - cp6; }
    }
  }
  __syncthreads();

  const int b32b = (k32 > 0) ? bbin[1] : -1;
  const int b16b = (k16 > 0) ? bbin[0] : -1;
  for (int i = tid; i < cnt; i += 256) {
    unsigned long long key = keys[i];
    float d2 = __uint_as_float((unsigned)(key >> 32));
    int b = min((int)(d2 * 6400.0f), 255);
    if (b == b32b) { int p = atomicAdd(&tmpcnt[1], 1); if (p < FTMP_CAP) tmpb[1][p] = key; }
    if (d2 <= 0.01f && min(b, 63) == b16b) {
      int p = atomicAdd(&tmpcnt[0], 1); if (p < FTMP_CAP) tmpb[0][p] = key;
    }
  }
  __syncthreads();

  if (wv < 2) {
    const int s = 1 - wv;
    const int k = s ? k32 : k16;
    if (k > 0) {
      const int h = min(tmpcnt[s], FTMP_CAP);
      const int m = msel[s];
      for (int base = 0; base < h; base += 64) {
        int ii = base + lane;
        if (ii < h) {
          unsigned long long e = tmpb[s][ii];
          int less = 0;
          for (int j = 0; j < h; ++j) less += (tmpb[s][j] < e) ? 1 : 0;
          if (less == m - 1) T_lds[s] = e;
        }
      }
    }
  }
  __syncthreads();

  {
    const unsigned long long T32 = (k32 > 0) ? T_lds[1] : 0ULL;
    const unsigned long long T16 = T_lds[0];
    for (int i = tid; i < cnt; i += 256) {
      unsigned long long key = keys[i];
      if (k32 > 0 && key <= T32) {
        float d2 = __uint_as_float((unsigned)(key >> 32));
        int idx = (int)(key & 0xffffffffu);
        float rx = ppts[idx * 3 + 0] - qx;
        float ry = ppts[idx * 3 + 1] - qy;
        float rz = ppts[idx * 3 + 2] - qz;
        bool f16 = (k16 > 0) && (d2 <= 0.01f) && (key <= T16);
        int slot = atomicAdd(&selcnt, 1);
        if (slot < 32) sel[slot] = make_float4(rx, ry, rz, f16 ? 1.0f : 0.0f);
      }
    }
  }
  __syncthreads();

  {
    const int nsel = min(selcnt, 32);
    const int scale = tid >> 7;
    const int h = tid & 127;
    const float w0 = W1[(scale * 3 + 0) * 128 + h];
    const float w1 = W1[(scale * 3 + 1) * 128 + h];
    const float w2 = W1[(scale * 3 + 2) * 128 + h];
    const float bb = b1[scale * 128 + h];
    float maxv = -INFINITY;
    for (int j = 0; j < nsel; ++j) {
      float4 e = sel[j];
      float val = e.x * w0 + e.y * w1 + e.z * w2;
      bool ok = scale ? true : (e.w > 0.5f);
      maxv = ok ? fmaxf(maxv, val) : maxv;
    }
    f_lds[tid] = fmaxf(maxv + bb, 0.0f);
  }
  __syncthreads();

  float* part = (float*)keys;
  {
    float4 acc = make_float4(0.f, 0.f, 0.f, 0.f);
    for (int r = 0; r < 64; ++r) {
      float fv = f_lds[wv * 64 + r];
      float4 w = ((const float4*)W2)[(wv * 64 + r) * 64 + lane];
      acc.x += fv * w.x; acc.y += fv * w.y; acc.z += fv * w.z; acc.w += fv * w.w;
    }
    ((float4*)part)[wv * 64 + lane] = acc;
  }
  __syncthreads();
  {
    float sum = part[0 * 256 + tid] + part[1 * 256 + tid] + part[2 * 256 + tid] +
                part[3 * 256 + tid] + b2[tid];
    out[q * 256 + tid] += sum;
  }
}

extern "C" void kernel_launch(void* const* d_in, const int* in_sizes, int n_in,
                              void* d_out, int out_size, void* d_ws, size_t ws_size,
                              hipStream_t stream) {
  const float* g      = (const float*)d_in[0];
  const float* s      = (const float*)d_in[1];
  const float* v      = (const float*)d_in[2];
  const float* geo_t  = (const float*)d_in[3];
  const float* surf_t = (const float*)d_in[4];
  const float* vol_t  = (const float*)d_in[5];
  const float* W1     = (const float*)d_in[6];
  const float* b1     = (const float*)d_in[7];
  const float* W2     = (const float*)d_in[8];
  const float* b2     = (const float*)d_in[9];
  float* out = (float*)d_out;

  const int NG = 4096, NS = 4096, NV = 8192;
  float* out_g = out;
  float* out_s = out + NG * 256;
  float* out_v = out + (NG + NS) * 256;

  const int total = (NG + NS + NV) * 256;
  hipLaunchKernelGGL(init_out_kernel, dim3(total / 256), dim3(256), 0, stream,
                     geo_t, surf_t, vol_t, out);

  const size_t need = (size_t)NV * 256 * sizeof(float);
  if (ws_size >= need) {
    float* fbuf = (float*)d_ws;
    auto launch = [&](int stack, const float* qp, int Nq, const float* pp, int Np, float* o) {
      hipLaunchKernelGGL(bq_select_pool_kernel, dim3(Nq / 4), dim3(256), 0, stream,
                         qp, pp, Np, W1 + stack * 768, b1 + stack * 256, fbuf);
      hipLaunchKernelGGL(bq_gemm_kernel, dim3(Nq / 16), dim3(256), 0, stream,
                         fbuf, W2 + stack * 256 * 256, b2 + stack * 256, o);
    };
    launch(0, g, NG, g, NG, out_g);
    launch(3, g, NG, s, NS, out_g);
    launch(4, g, NG, v, NV, out_g);
    launch(1, s, NS, s, NS, out_s);
    launch(5, s, NS, g, NG, out_s);
    launch(2, v, NV, v, NV, out_v);
    launch(6, v, NV, g, NG, out_v);
  } else {
    auto launch = [&](int stack, const float* qp, int Nq, const float* pp, int Np, float* o) {
      hipLaunchKernelGGL(bq_stack_fused, dim3(Nq), dim3(256), 0, stream,
                         qp, pp, Np, W1 + stack * 768, b1 + stack * 256,
                         W2 + stack * 256 * 256, b2 + stack * 256, o);
    };
    launch(0, g, NG, g, NG, out_g);
    launch(3, g, NG, s, NS, out_g);
    launch(4, g, NG, v, NV, out_g);
    launch(1, s, NS, s, NS, out_s);
    launch(5, s, NS, g, NG, out_s);
    launch(2, v, NV, v, NV, out_v);
    launch(6, v, NV, g, NG, out_v);
  }
}

// Round 5
// 320.485 us; speedup vs baseline: 3.4176x; 1.6020x over previous
//
#include <hip/hip_runtime.h>

#define CAND_CAP 512
#define TMP_CAP 64
#define M_MAX 1024
#define FTMP_CAP 128

// ============================ grid build kernels ============================
// 1000 cells (10^3, cell=0.1) per point set; sets: 0=g(4096) 1=s(4096) 2=v(8192).
// ws layout (mode A/B): [fbuf][starts 3*1024 int][cursor 3*1024 int][binned 16384 float4]

__device__ __forceinline__ int cell_of(float x, float y, float z) {
  int cx = min((int)(x * 10.0f), 9);
  int cy = min((int)(y * 10.0f), 9);
  int cz = min((int)(z * 10.0f), 9);
  return cz * 100 + cy * 10 + cx;
}

__global__ __launch_bounds__(256) void grid_count_kernel(
    const float* __restrict__ g, const float* __restrict__ s, const float* __restrict__ v,
    int* __restrict__ counts) {
  int i = blockIdx.x * 256 + threadIdx.x;  // 0..16383
  const float* p; int set, local;
  if (i < 4096)      { set = 0; p = g; local = i; }
  else if (i < 8192) { set = 1; p = s; local = i - 4096; }
  else               { set = 2; p = v; local = i - 8192; }
  float x = p[local * 3 + 0], y = p[local * 3 + 1], z = p[local * 3 + 2];
  atomicAdd(&counts[set * 1024 + cell_of(x, y, z)], 1);
}

__global__ __launch_bounds__(1024) void grid_scan_kernel(
    int* __restrict__ counts,   // in: counts; out: cursor (= exclusive start)
    int* __restrict__ starts) { // out: exclusive prefix, starts[1000] = total
  __shared__ int sdata[1024];
  const int tid = threadIdx.x, set = blockIdx.x;
  int v = (tid < 1000) ? counts[set * 1024 + tid] : 0;
  sdata[tid] = v;
  __syncthreads();
  for (int off = 1; off < 1024; off <<= 1) {
    int t = (tid >= off) ? sdata[tid - off] : 0;
    __syncthreads();
    sdata[tid] += t;
    __syncthreads();
  }
  int incl = sdata[tid];
  int excl = incl - v;
  if (tid < 1000) {
    starts[set * 1024 + tid] = excl;
    counts[set * 1024 + tid] = excl;  // becomes cursor
    if (tid == 999) starts[set * 1024 + 1000] = incl;
  }
}

__global__ __launch_bounds__(256) void grid_scatter_kernel(
    const float* __restrict__ g, const float* __restrict__ s, const float* __restrict__ v,
    int* __restrict__ cursor, float4* __restrict__ binned) {
  int i = blockIdx.x * 256 + threadIdx.x;
  const float* p; int set, local, base;
  if (i < 4096)      { set = 0; p = g; local = i;        base = 0;    }
  else if (i < 8192) { set = 1; p = s; local = i - 4096; base = 4096; }
  else               { set = 2; p = v; local = i - 8192; base = 8192; }
  float x = p[local * 3 + 0], y = p[local * 3 + 1], z = p[local * 3 + 2];
  int pos = atomicAdd(&cursor[set * 1024 + cell_of(x, y, z)], 1);
  binned[base + pos] = make_float4(x, y, z, __int_as_float(local));
}

// ============================ merged select kernel ============================
struct SelDesc {
  const float* qptr[7];
  int pbase[7];     // binned element base for the stack's point set
  int soff[7];      // starts offset = set*1024
  int w1off[7];     // stack*768
  int b1off[7];     // stack*256
  int foff[7];      // fbuf row offset
  int blkstart[8];  // cumulative blocks (4 queries/block)
};

__global__ __launch_bounds__(256) void bq_select_grid(
    SelDesc d, const float* __restrict__ W1all, const float* __restrict__ b1all,
    const float4* __restrict__ binned, const int* __restrict__ starts,
    float* __restrict__ fbuf) {
  __shared__ unsigned long long keys[4][CAND_CAP];
  __shared__ unsigned short posA[4][CAND_CAP];
  __shared__ unsigned long long tmpb[4][2][TMP_CAP];
  __shared__ unsigned long long Tkey[4][2];
  __shared__ int hist32[4][256];
  __shared__ int hist16[4][64];
  __shared__ int wcnt[4], scnt[4];
  __shared__ int tmpcnt[4][2];
  __shared__ int bbin[4][2];
  __shared__ int msel[4][2];
  __shared__ float4 sel[4][32];

  const int tid = threadIdx.x, lane = tid & 63, wv = tid >> 6;

  int st = 0;
  while ((int)blockIdx.x >= d.blkstart[st + 1]) ++st;
  const int qlocal = ((int)blockIdx.x - d.blkstart[st]) * 4 + wv;
  const float* qpts = d.qptr[st];
  const int pbase = d.pbase[st];
  const int soff = d.soff[st];

  // per-wave init
#pragma unroll
  for (int i = 0; i < 4; ++i) hist32[wv][lane + 64 * i] = 0;
  hist16[wv][lane] = 0;
  if (lane == 0) {
    wcnt[wv] = 0; scnt[wv] = 0;
    tmpcnt[wv][0] = 0; tmpcnt[wv][1] = 0;
    Tkey[wv][0] = 0; Tkey[wv][1] = 0;
    bbin[wv][0] = -1; bbin[wv][1] = -1;
    msel[wv][0] = 0; msel[wv][1] = 0;
  }
  const float qx = qpts[qlocal * 3 + 0];
  const float qy = qpts[qlocal * 3 + 1];
  const float qz = qpts[qlocal * 3 + 2];
  __builtin_amdgcn_wave_barrier();
  __threadfence_block();

  // cell-range scan: 5x5x5 block covering the r=0.2 sphere, row-culled
  const int cx0 = max(0, (int)floorf((qx - 0.2f) * 10.0f));
  const int cx1 = min(9, (int)floorf((qx + 0.2f) * 10.0f));
  const int cy0 = max(0, (int)floorf((qy - 0.2f) * 10.0f));
  const int cy1 = min(9, (int)floorf((qy + 0.2f) * 10.0f));
  const int cz0 = max(0, (int)floorf((qz - 0.2f) * 10.0f));
  const int cz1 = min(9, (int)floorf((qz + 0.2f) * 10.0f));

  for (int cz = cz0; cz <= cz1; ++cz) {
    float lo = cz * 0.1f;
    float dz = fmaxf(fmaxf(lo - qz, qz - (lo + 0.1f)), 0.0f);
    float dz2 = dz * dz;
    for (int cy = cy0; cy <= cy1; ++cy) {
      float loy = cy * 0.1f;
      float dy = fmaxf(fmaxf(loy - qy, qy - (loy + 0.1f)), 0.0f);
      if (dz2 + dy * dy > 0.04f) continue;
      int row = cz * 100 + cy * 10;
      int beg = starts[soff + row + cx0];
      int end = starts[soff + row + cx1 + 1];
      for (int i = beg + lane; i < end; i += 64) {
        float4 P = binned[pbase + i];
        float dx = P.x - qx, dyy = P.y - qy, dzz = P.z - qz;
        float d2 = dx * dx + dyy * dyy + dzz * dzz;
        if (d2 <= 0.04f) {
          int pos = atomicAdd(&wcnt[wv], 1);
          if (pos < CAND_CAP) {
            keys[wv][pos] = ((unsigned long long)__float_as_uint(d2) << 32) |
                            (unsigned)__float_as_int(P.w);
            posA[wv][pos] = (unsigned short)i;
          }
          int b = min((int)(d2 * 6400.0f), 255);
          atomicAdd(&hist32[wv][b], 1);
          if (d2 <= 0.01f) atomicAdd(&hist16[wv][min(b, 63)], 1);
        }
      }
    }
  }
  __builtin_amdgcn_wave_barrier();
  __threadfence_block();
  const int cnt = min(wcnt[wv], CAND_CAP);
  const int k32 = min(32, cnt);

  // prefix scan hist32 (lane owns 4 bins) + boundary bin for k32
  {
    int h0 = hist32[wv][lane * 4 + 0];
    int h1 = hist32[wv][lane * 4 + 1];
    int h2 = hist32[wv][lane * 4 + 2];
    int h3 = hist32[wv][lane * 4 + 3];
    int c1 = h0 + h1, c2 = c1 + h2, c3 = c2 + h3;
    int incl = c3;
#pragma unroll
    for (int o = 1; o < 64; o <<= 1) {
      int t = __shfl_up(incl, o, 64);
      if (lane >= o) incl += t;
    }
    int off = incl - c3;
    if (k32 > 0) {
      int cum0 = off + h0, cum1 = off + c1, cum2 = off + c2, cum3 = off + c3;
      if (cum0 >= k32 && off  < k32) { bbin[wv][1] = lane * 4 + 0; msel[wv][1] = k32 - off;  }
      if (cum1 >= k32 && cum0 < k32) { bbin[wv][1] = lane * 4 + 1; msel[wv][1] = k32 - cum0; }
      if (cum2 >= k32 && cum1 < k32) { bbin[wv][1] = lane * 4 + 2; msel[wv][1] = k32 - cum1; }
      if (cum3 >= k32 && cum2 < k32) { bbin[wv][1] = lane * 4 + 3; msel[wv][1] = k32 - cum2; }
    }
  }
  // hist16 scan + boundary bin for k16
  int k16;
  {
    int gg = hist16[wv][lane];
    int incl = gg;
#pragma unroll
    for (int o = 1; o < 64; o <<= 1) {
      int t = __shfl_up(incl, o, 64);
      if (lane >= o) incl += t;
    }
    int tot = __shfl(incl, 63, 64);
    k16 = min(16, tot);
    if (k16 > 0) {
      int prev = incl - gg;
      if (incl >= k16 && prev < k16) { bbin[wv][0] = lane; msel[wv][0] = k16 - prev; }
    }
  }
  __builtin_amdgcn_wave_barrier();
  __threadfence_block();
  const int b32b = bbin[wv][1];
  const int b16b = bbin[wv][0];

  // collect boundary-bin keys
  for (int i = lane; i < cnt; i += 64) {
    unsigned long long key = keys[wv][i];
    float d2 = __uint_as_float((unsigned)(key >> 32));
    int b = min((int)(d2 * 6400.0f), 255);
    if (b == b32b) { int p = atomicAdd(&tmpcnt[wv][1], 1); if (p < TMP_CAP) tmpb[wv][1][p] = key; }
    if (d2 <= 0.01f && min(b, 63) == b16b) {
      int p = atomicAdd(&tmpcnt[wv][0], 1); if (p < TMP_CAP) tmpb[wv][0][p] = key;
    }
  }
  __builtin_amdgcn_wave_barrier();
  __threadfence_block();

  // rank-select m-th smallest key in each boundary bin
#pragma unroll
  for (int s = 0; s < 2; ++s) {
    const int k = s ? k32 : k16;
    if (k > 0) {
      const int h = min(tmpcnt[wv][s], TMP_CAP);
      const int m = msel[wv][s];
      for (int base = 0; base < h; base += 64) {
        int ii = base + lane;
        if (ii < h) {
          unsigned long long e = tmpb[wv][s][ii];
          int less = 0;
          for (int j = 0; j < h; ++j) less += (tmpb[wv][s][j] < e) ? 1 : 0;
          if (less == m - 1) Tkey[wv][s] = e;
        }
      }
    }
  }
  __builtin_amdgcn_wave_barrier();
  __threadfence_block();
  const unsigned long long T32 = Tkey[wv][1];
  const unsigned long long T16 = Tkey[wv][0];

  // compact selected neighbors (exactly k32; scale-0 membership flagged)
  for (int i = lane; i < cnt; i += 64) {
    unsigned long long key = keys[wv][i];
    if (k32 > 0 && key <= T32) {
      float4 P = binned[pbase + posA[wv][i]];
      float d2 = __uint_as_float((unsigned)(key >> 32));
      bool f16 = (k16 > 0) && (d2 <= 0.01f) && (key <= T16);
      int slot = atomicAdd(&scnt[wv], 1);
      if (slot < 32) sel[wv][slot] = make_float4(P.x - qx, P.y - qy, P.z - qz, f16 ? 1.0f : 0.0f);
    }
  }
  __builtin_amdgcn_wave_barrier();
  __threadfence_block();
  const int nsel = min(scnt[wv], 32);

  // masked max-pool; lane covers 4 channels (lanes<32: scale0, else scale1)
  {
    const float* W1 = W1all + d.w1off[st];
    const float* b1 = b1all + d.b1off[st];
    const int scale = lane >> 5;
    const int hbase = (lane & 31) * 4;
    const float4 wx = *(const float4*)(W1 + scale * 384 + 0 * 128 + hbase);
    const float4 wy = *(const float4*)(W1 + scale * 384 + 1 * 128 + hbase);
    const float4 wz = *(const float4*)(W1 + scale * 384 + 2 * 128 + hbase);
    const float4 bb = *(const float4*)(b1 + scale * 128 + hbase);
    float m0 = -INFINITY, m1 = -INFINITY, m2 = -INFINITY, m3 = -INFINITY;
    for (int n = 0; n < nsel; ++n) {
      float4 e = sel[wv][n];
      bool ok = scale ? true : (e.w > 0.5f);
      float v0 = e.x * wx.x + e.y * wy.x + e.z * wz.x;
      float v1 = e.x * wx.y + e.y * wy.y + e.z * wz.y;
      float v2 = e.x * wx.z + e.y * wy.z + e.z * wz.z;
      float v3 = e.x * wx.w + e.y * wy.w + e.z * wz.w;
      if (ok) { m0 = fmaxf(m0, v0); m1 = fmaxf(m1, v1); m2 = fmaxf(m2, v2); m3 = fmaxf(m3, v3); }
    }
    float4 f4 = make_float4(fmaxf(m0 + bb.x, 0.0f), fmaxf(m1 + bb.y, 0.0f),
                            fmaxf(m2 + bb.z, 0.0f), fmaxf(m3 + bb.w, 0.0f));
    *(float4*)(fbuf + (long)(d.foff[st] + qlocal) * 256 + lane * 4) = f4;
  }
}

// ============================ merged GEMM kernel ============================
// out[q] = base[q] + sum_stacks (f_s[q] @ W2_s) + sum b2_s   (16 queries/block)
struct GemmDesc {
  const float* basep[3];
  float* outp[3];
  int blkstart[4];
  int nst[3];
  int foff[3][3];
  int w2off[3][3];
  int b2off[3][3];
};

#define FMA4(acc, s_, W_) { (acc).x += (s_) * (W_).x; (acc).y += (s_) * (W_).y; (acc).z += (s_) * (W_).z; (acc).w += (s_) * (W_).w; }

__global__ __launch_bounds__(256) void bq_gemm_multi(
    GemmDesc d, const float* __restrict__ W2all, const float* __restrict__ b2all,
    const float* __restrict__ fbuf) {
  __shared__ float ftile[16 * 256];
  const int tid = threadIdx.x, lane = tid & 63, wv = tid >> 6;

  int rg = 0;
  while ((int)blockIdx.x >= d.blkstart[rg + 1]) ++rg;
  const int qb = ((int)blockIdx.x - d.blkstart[rg]) * 16;

  float4 acc0 = make_float4(0.f,0.f,0.f,0.f), acc1 = acc0, acc2 = acc0, acc3 = acc0;
  float4 bbsum = acc0;

  const int nst = d.nst[rg];
  for (int s = 0; s < nst; ++s) {
    __syncthreads();  // protect ftile from previous iteration's readers
    {
      const float4* src = (const float4*)(fbuf + (long)(d.foff[rg][s] + qb) * 256);
      float4* dst = (float4*)ftile;
#pragma unroll
      for (int i = 0; i < 4; ++i) dst[tid + 256 * i] = src[tid + 256 * i];
    }
    __syncthreads();
    const float4* w24 = (const float4*)(W2all + d.w2off[rg][s]);
    const float* fb = ftile + wv * 4 * 256;
    for (int f = 0; f < 256; f += 4) {
      float4 fq0 = *(const float4*)(fb + 0 * 256 + f);
      float4 fq1 = *(const float4*)(fb + 1 * 256 + f);
      float4 fq2 = *(const float4*)(fb + 2 * 256 + f);
      float4 fq3 = *(const float4*)(fb + 3 * 256 + f);
      float4 w0 = w24[(f + 0) * 64 + lane];
      float4 w1 = w24[(f + 1) * 64 + lane];
      float4 w2 = w24[(f + 2) * 64 + lane];
      float4 w3 = w24[(f + 3) * 64 + lane];
      FMA4(acc0, fq0.x, w0) FMA4(acc0, fq0.y, w1) FMA4(acc0, fq0.z, w2) FMA4(acc0, fq0.w, w3)
      FMA4(acc1, fq1.x, w0) FMA4(acc1, fq1.y, w1) FMA4(acc1, fq1.z, w2) FMA4(acc1, fq1.w, w3)
      FMA4(acc2, fq2.x, w0) FMA4(acc2, fq2.y, w1) FMA4(acc2, fq2.z, w2) FMA4(acc2, fq2.w, w3)
      FMA4(acc3, fq3.x, w0) FMA4(acc3, fq3.y, w1) FMA4(acc3, fq3.z, w2) FMA4(acc3, fq3.w, w3)
    }
    float4 bb = ((const float4*)(b2all + d.b2off[rg][s]))[lane];
    bbsum.x += bb.x; bbsum.y += bb.y; bbsum.z += bb.z; bbsum.w += bb.w;
  }

  const float4* base4 = (const float4*)d.basep[rg];
  float4* out4 = (float4*)d.outp[rg];
#pragma unroll
  for (int j = 0; j < 4; ++j) {
    float4 a = (j == 0) ? acc0 : (j == 1) ? acc1 : (j == 2) ? acc2 : acc3;
    int q = qb + wv * 4 + j;
    float4 o = base4[q * 64 + lane];
    o.x += a.x + bbsum.x; o.y += a.y + bbsum.y; o.z += a.z + bbsum.z; o.w += a.w + bbsum.w;
    out4[q * 64 + lane] = o;
  }
}

// ============================ fused fallback (tiny ws) ============================
__global__ __launch_bounds__(256) void init_out_kernel(
    const float* __restrict__ g, const float* __restrict__ s, const float* __restrict__ v,
    float* __restrict__ out) {
  const int NG = 4096 * 256, NS = 4096 * 256;
  int i = blockIdx.x * 256 + threadIdx.x;
  if (i < NG) out[i] = g[i];
  else if (i < NG + NS) out[i] = s[i - NG];
  else out[i] = v[i - NG - NS];
}

__global__ __launch_bounds__(256) void bq_stack_fused(
    const float* __restrict__ qpts,
    const float* __restrict__ ppts, int Np,
    const float* __restrict__ W1, const float* __restrict__ b1,
    const float* __restrict__ W2, const float* __restrict__ b2,
    float* __restrict__ out) {
  __shared__ unsigned long long keys[M_MAX];
  __shared__ int hist32[256];
  __shared__ int hist16[64];
  __shared__ unsigned long long tmpb[2][FTMP_CAP];
  __shared__ int tmpcnt[2];
  __shared__ float4 sel[32];
  __shared__ int selcnt;
  __shared__ float f_lds[256];
  __shared__ int cnt_s;
  __shared__ unsigned long long T_lds[2];
  __shared__ int bbin[2], msel[2];
  __shared__ int wsum[4];
  __shared__ float qsh[3];

  const int tid = threadIdx.x;
  const int lane = tid & 63;
  const int wv = tid >> 6;
  const int q = blockIdx.x;

  hist32[tid] = 0;
  if (tid < 64) hist16[tid] = 0;
  if (tid == 0) {
    cnt_s = 0; selcnt = 0; tmpcnt[0] = 0; tmpcnt[1] = 0;
    T_lds[0] = ~0ULL; T_lds[1] = ~0ULL;
    qsh[0] = qpts[q * 3 + 0]; qsh[1] = qpts[q * 3 + 1]; qsh[2] = qpts[q * 3 + 2];
  }
  __syncthreads();
  const float qx = qsh[0], qy = qsh[1], qz = qsh[2];

  const float4* pp4 = (const float4*)ppts;
  const int groups = Np >> 2;
  for (int gp = tid; gp < groups; gp += 256) {
    float4 A = pp4[gp * 3 + 0];
    float4 Bv = pp4[gp * 3 + 1];
    float4 C = pp4[gp * 3 + 2];
    float px[4] = {A.x, A.w, Bv.z, C.y};
    float py[4] = {A.y, Bv.x, Bv.w, C.z};
    float pz[4] = {A.z, Bv.y, C.x, C.w};
#pragma unroll
    for (int t = 0; t < 4; ++t) {
      float dx = px[t] - qx, dy = py[t] - qy, dz = pz[t] - qz;
      float d2 = dx * dx + dy * dy + dz * dz;
      if (d2 <= 0.04f) {
        int pos = atomicAdd(&cnt_s, 1);
        if (pos < M_MAX)
          keys[pos] = ((unsigned long long)__float_as_uint(d2) << 32) | (unsigned)(gp * 4 + t);
        int b = min((int)(d2 * 6400.0f), 255);
        atomicAdd(&hist32[b], 1);
        if (d2 <= 0.01f) atomicAdd(&hist16[min(b, 63)], 1);
      }
    }
  }
  __syncthreads();
  const int cnt = min(cnt_s, M_MAX);

  {
    int v = hist32[tid];
#pragma unroll
    for (int o = 1; o < 64; o <<= 1) {
      int t = __shfl_up(v, o, 64);
      if (lane >= o) v += t;
    }
    if (lane == 63) wsum[wv] = v;
    int v16 = 0;
    if (wv == 0) {
      v16 = hist16[lane];
#pragma unroll
      for (int o = 1; o < 64; o <<= 1) {
        int t = __shfl_up(v16, o, 64);
        if (lane >= o) v16 += t;
      }
    }
    __syncthreads();
    int off = 0;
    for (int w = 0; w < wv; ++w) off += wsum[w];
    hist32[tid] = v + off;
    if (wv == 0) hist16[lane] = v16;
    __syncthreads();
  }

  const int k32 = min(32, cnt);
  const int c16tot = hist16[63];
  const int k16 = min(16, c16tot);

  {
    int c = hist32[tid], cp = tid ? hist32[tid - 1] : 0;
    if (k32 > 0 && c >= k32 && cp < k32) { bbin[1] = tid; msel[1] = k32 - cp; }
    if (tid < 64) {
      int c6 = hist16[tid], cp6 = tid ? hist16[tid - 1] : 0;
      if (k16 > 0 && c6 >= k16 && cp6 < k16) { bbin[0] = tid; msel[0] = k16 - cp6; }
    }
  }
  __syncthreads();

  const int b32b = (k32 > 0) ? bbin[1] : -1;
  const int b16b = (k16 > 0) ? bbin[0] : -1;
  for (int i = tid; i < cnt; i += 256) {
    unsigned long long key = keys[i];
    float d2 = __uint_as_float((unsigned)(key >> 32));
    int b = min((int)(d2 * 6400.0f), 255);
    if (b == b32b) { int p = atomicAdd(&tmpcnt[1], 1); if (p < FTMP_CAP) tmpb[1][p] = key; }
    if (d2 <= 0.01f && min(b, 63) == b16b) {
      int p = atomicAdd(&tmpcnt[0], 1); if (p < FTMP_CAP) tmpb[0][p] = key;
    }
  }
  __syncthreads();

  if (wv < 2) {
    const int s = 1 - wv;
    const int k = s ? k32 : k16;
    if (k > 0) {
      const int h = min(tmpcnt[s], FTMP_CAP);
      const int m = msel[s];
      for (int base = 0; base < h; base += 64) {
        int ii = base + lane;
        if (ii < h) {
          unsigned long long e = tmpb[s][ii];
          int less = 0;
          for (int j = 0; j < h; ++j) less += (tmpb[s][j] < e) ? 1 : 0;
          if (less == m - 1) T_lds[s] = e;
        }
      }
    }
  }
  __syncthreads();

  {
    const unsigned long long T32 = (k32 > 0) ? T_lds[1] : 0ULL;
    const unsigned long long T16 = T_lds[0];
    for (int i = tid; i < cnt; i += 256) {
      unsigned long long key = keys[i];
      if (k32 > 0 && key <= T32) {
        float d2 = __uint_as_float((unsigned)(key >> 32));
        int idx = (int)(key & 0xffffffffu);
        float rx = ppts[idx * 3 + 0] - qx;
        float ry = ppts[idx * 3 + 1] - qy;
        float rz = ppts[idx * 3 + 2] - qz;
        bool f16 = (k16 > 0) && (d2 <= 0.01f) && (key <= T16);
        int slot = atomicAdd(&selcnt, 1);
        if (slot < 32) sel[slot] = make_float4(rx, ry, rz, f16 ? 1.0f : 0.0f);
      }
    }
  }
  __syncthreads();

  {
    const int nsel = min(selcnt, 32);
    const int scale = tid >> 7;
    const int h = tid & 127;
    const float w0 = W1[(scale * 3 + 0) * 128 + h];
    const float w1 = W1[(scale * 3 + 1) * 128 + h];
    const float w2 = W1[(scale * 3 + 2) * 128 + h];
    const float bb = b1[scale * 128 + h];
    float maxv = -INFINITY;
    for (int j = 0; j < nsel; ++j) {
      float4 e = sel[j];
      float val = e.x * w0 + e.y * w1 + e.z * w2;
      bool ok = scale ? true : (e.w > 0.5f);
      maxv = ok ? fmaxf(maxv, val) : maxv;
    }
    f_lds[tid] = fmaxf(maxv + bb, 0.0f);
  }
  __syncthreads();

  float* part = (float*)keys;
  {
    float4 acc = make_float4(0.f, 0.f, 0.f, 0.f);
    for (int r = 0; r < 64; ++r) {
      float fv = f_lds[wv * 64 + r];
      float4 w = ((const float4*)W2)[(wv * 64 + r) * 64 + lane];
      acc.x += fv * w.x; acc.y += fv * w.y; acc.z += fv * w.z; acc.w += fv * w.w;
    }
    ((float4*)part)[wv * 64 + lane] = acc;
  }
  __syncthreads();
  {
    float sum = part[0 * 256 + tid] + part[1 * 256 + tid] + part[2 * 256 + tid] +
                part[3 * 256 + tid] + b2[tid];
    out[q * 256 + tid] += sum;
  }
}

// ============================ launch ============================
extern "C" void kernel_launch(void* const* d_in, const int* in_sizes, int n_in,
                              void* d_out, int out_size, void* d_ws, size_t ws_size,
                              hipStream_t stream) {
  const float* g      = (const float*)d_in[0];
  const float* s      = (const float*)d_in[1];
  const float* v      = (const float*)d_in[2];
  const float* geo_t  = (const float*)d_in[3];
  const float* surf_t = (const float*)d_in[4];
  const float* vol_t  = (const float*)d_in[5];
  const float* W1     = (const float*)d_in[6];
  const float* b1     = (const float*)d_in[7];
  const float* W2     = (const float*)d_in[8];
  const float* b2     = (const float*)d_in[9];
  float* out = (float*)d_out;

  const int NG = 4096, NS = 4096, NV = 8192;
  float* out_g = out;
  float* out_s = out + NG * 256;
  float* out_v = out + (NG + NS) * 256;

  // stack order and metadata (matches reference composition)
  const int stackid[7] = {0, 3, 4, 1, 5, 2, 6};
  const float* qp[7]   = {g, g, g, s, s, v, v};
  const int    nq[7]   = {NG, NG, NG, NS, NS, NV, NV};
  const int    pset[7] = {0, 1, 2, 1, 0, 2, 0};   // point set per stack (g=0,s=1,v=2)
  const int    setbase[3] = {0, 4096, 8192};

  const size_t GRID_INTS = 3 * 1024;
  const size_t fbufA = (size_t)36864 * 256 * sizeof(float);
  const size_t fbufB = (size_t)8192 * 256 * sizeof(float);
  const size_t tailBytes = GRID_INTS * 4 * 2 + (size_t)16384 * sizeof(float4);
  const size_t needA = fbufA + tailBytes;
  const size_t needB = fbufB + tailBytes;

  if (ws_size >= needB) {
    const bool modeA = (ws_size >= needA);
    const size_t fbytes = modeA ? fbufA : fbufB;
    float* fbuf   = (float*)d_ws;
    int*   starts = (int*)((char*)d_ws + fbytes);
    int*   cursor = (int*)((char*)d_ws + fbytes + GRID_INTS * 4);
    float4* binned = (float4*)((char*)d_ws + fbytes + GRID_INTS * 8);

    // grid build
    hipMemsetAsync(cursor, 0, GRID_INTS * 4, stream);
    hipLaunchKernelGGL(grid_count_kernel, dim3(64), dim3(256), 0, stream, g, s, v, cursor);
    hipLaunchKernelGGL(grid_scan_kernel, dim3(3), dim3(1024), 0, stream, cursor, starts);
    hipLaunchKernelGGL(grid_scatter_kernel, dim3(64), dim3(256), 0, stream, g, s, v, cursor, binned);

    if (modeA) {
      SelDesc sd;
      int blk = 0, frow = 0;
      for (int i = 0; i < 7; ++i) {
        sd.qptr[i] = qp[i];
        sd.pbase[i] = setbase[pset[i]];
        sd.soff[i] = pset[i] * 1024;
        sd.w1off[i] = stackid[i] * 768;
        sd.b1off[i] = stackid[i] * 256;
        sd.foff[i] = frow;
        sd.blkstart[i] = blk;
        blk += nq[i] / 4;
        frow += nq[i];
      }
      sd.blkstart[7] = blk;
      hipLaunchKernelGGL(bq_select_grid, dim3(blk), dim3(256), 0, stream,
                         sd, W1, b1, binned, starts, fbuf);

      GemmDesc gd;
      gd.basep[0] = geo_t;  gd.outp[0] = out_g;
      gd.basep[1] = surf_t; gd.outp[1] = out_s;
      gd.basep[2] = vol_t;  gd.outp[2] = out_v;
      gd.blkstart[0] = 0;
      gd.blkstart[1] = NG / 16;
      gd.blkstart[2] = NG / 16 + NS / 16;
      gd.blkstart[3] = NG / 16 + NS / 16 + NV / 16;
      gd.nst[0] = 3; gd.nst[1] = 2; gd.nst[2] = 2;
      // region g: select-order indices 0,1,2 ; s: 3,4 ; v: 5,6
      const int ridx[3][3] = {{0, 1, 2}, {3, 4, -1}, {5, 6, -1}};
      int foffs[7]; int fr = 0;
      for (int i = 0; i < 7; ++i) { foffs[i] = fr; fr += nq[i]; }
      for (int r = 0; r < 3; ++r)
        for (int t = 0; t < gd.nst[r]; ++t) {
          int i = ridx[r][t];
          gd.foff[r][t] = foffs[i];
          gd.w2off[r][t] = stackid[i] * 256 * 256;
          gd.b2off[r][t] = stackid[i] * 256;
        }
      hipLaunchKernelGGL(bq_gemm_multi, dim3(gd.blkstart[3]), dim3(256), 0, stream,
                         gd, W2, b2, fbuf);
    } else {
      // mode B: per-stack select + gemm with fbuf reuse; first stack of each
      // region uses token base, later stacks read/accumulate from out.
      const float* bases[7] = {geo_t, out_g, out_g, surf_t, out_s, vol_t, out_v};
      float* outs[7] = {out_g, out_g, out_g, out_s, out_s, out_v, out_v};
      for (int i = 0; i < 7; ++i) {
        SelDesc sd;
        sd.qptr[0] = qp[i];
        sd.pbase[0] = setbase[pset[i]];
        sd.soff[0] = pset[i] * 1024;
        sd.w1off[0] = stackid[i] * 768;
        sd.b1off[0] = stackid[i] * 256;
        sd.foff[0] = 0;
        sd.blkstart[0] = 0; sd.blkstart[1] = nq[i] / 4;
        for (int j = 2; j < 8; ++j) sd.blkstart[j] = nq[i] / 4;
        hipLaunchKernelGGL(bq_select_grid, dim3(nq[i] / 4), dim3(256), 0, stream,
                           sd, W1, b1, binned, starts, fbuf);
        GemmDesc gd;
        gd.basep[0] = bases[i]; gd.outp[0] = outs[i];
        gd.blkstart[0] = 0;
        gd.blkstart[1] = nq[i] / 16; gd.blkstart[2] = nq[i] / 16; gd.blkstart[3] = nq[i] / 16;
        gd.nst[0] = 1; gd.nst[1] = 0; gd.nst[2] = 0;
        gd.foff[0][0] = 0;
        gd.w2off[0][0] = stackid[i] * 256 * 256;
        gd.b2off[0][0] = stackid[i] * 256;
        hipLaunchKernelGGL(bq_gemm_multi, dim3(nq[i] / 16), dim3(256), 0, stream,
                           gd, W2, b2, fbuf);
      }
    }
  } else {
    // tiny-ws fallback: fully fused per-query kernel
    const int total = (NG + NS + NV) * 256;
    hipLaunchKernelGGL(init_out_kernel, dim3(total / 256), dim3(256), 0, stream,
                       geo_t, surf_t, vol_t, out);
    auto launch = [&](int stack, const float* qp_, int Nq, const float* pp_, int Np, float* o) {
      hipLaunchKernelGGL(bq_stack_fused, dim3(Nq), dim3(256), 0, stream,
                         qp_, pp_, Np, W1 + stack * 768, b1 + stack * 256,
                         W2 + stack * 256 * 256, b2 + stack * 256, o);
    };
    launch(0, g, NG, g, NG, out_g);
    launch(3, g, NG, s, NS, out_g);
    launch(4, g, NG, v, NV, out_g);
    launch(1, s, NS, s, NS, out_s);
    launch(5, s, NS, g, NG, out_s);
    launch(2, v, NV, v, NV, out_v);
    launch(6, v, NV, g, NG, out_v);
  }
}

// Round 6
// 231.617 us; speedup vs baseline: 4.7289x; 1.3837x over previous
//
#include <hip/hip_runtime.h>

#define CAND_CAP 448
#define TMP_CAP 32
#define M_MAX 1024
#define FTMP_CAP 128

typedef __attribute__((ext_vector_type(8))) short bf16x8;
typedef __attribute__((ext_vector_type(4))) float f32x4;

__device__ __forceinline__ unsigned short f2bf(float x) {
  unsigned u = __float_as_uint(x);
  unsigned r = (u + 0x7fffu + ((u >> 16) & 1u)) >> 16;
  return (unsigned short)r;
}

// ============================ grid build kernels ============================
__device__ __forceinline__ int cell_of(float x, float y, float z) {
  int cx = min((int)(x * 10.0f), 9);
  int cy = min((int)(y * 10.0f), 9);
  int cz = min((int)(z * 10.0f), 9);
  return cz * 100 + cy * 10 + cx;
}

__global__ __launch_bounds__(256) void grid_count_kernel(
    const float* __restrict__ g, const float* __restrict__ s, const float* __restrict__ v,
    int* __restrict__ counts) {
  int i = blockIdx.x * 256 + threadIdx.x;  // 0..16383
  const float* p; int set, local;
  if (i < 4096)      { set = 0; p = g; local = i; }
  else if (i < 8192) { set = 1; p = s; local = i - 4096; }
  else               { set = 2; p = v; local = i - 8192; }
  float x = p[local * 3 + 0], y = p[local * 3 + 1], z = p[local * 3 + 2];
  atomicAdd(&counts[set * 1024 + cell_of(x, y, z)], 1);
}

__global__ __launch_bounds__(1024) void grid_scan_kernel(
    int* __restrict__ counts, int* __restrict__ starts) {
  __shared__ int sdata[1024];
  const int tid = threadIdx.x, set = blockIdx.x;
  int v = (tid < 1000) ? counts[set * 1024 + tid] : 0;
  sdata[tid] = v;
  __syncthreads();
  for (int off = 1; off < 1024; off <<= 1) {
    int t = (tid >= off) ? sdata[tid - off] : 0;
    __syncthreads();
    sdata[tid] += t;
    __syncthreads();
  }
  int incl = sdata[tid];
  int excl = incl - v;
  if (tid < 1000) {
    starts[set * 1024 + tid] = excl;
    counts[set * 1024 + tid] = excl;  // becomes cursor
    if (tid == 999) starts[set * 1024 + 1000] = incl;
  }
}

__global__ __launch_bounds__(256) void grid_scatter_kernel(
    const float* __restrict__ g, const float* __restrict__ s, const float* __restrict__ v,
    int* __restrict__ cursor, float4* __restrict__ binned) {
  int i = blockIdx.x * 256 + threadIdx.x;
  const float* p; int set, local, base;
  if (i < 4096)      { set = 0; p = g; local = i;        base = 0;    }
  else if (i < 8192) { set = 1; p = s; local = i - 4096; base = 4096; }
  else               { set = 2; p = v; local = i - 8192; base = 8192; }
  float x = p[local * 3 + 0], y = p[local * 3 + 1], z = p[local * 3 + 2];
  int pos = atomicAdd(&cursor[set * 1024 + cell_of(x, y, z)], 1);
  binned[base + pos] = make_float4(x, y, z, __int_as_float(local));
}

// W2T[s][n][k] = bf16(W2[s][k][n]); grid 7*256 blocks, 256 threads
__global__ __launch_bounds__(256) void w2_convert_kernel(
    const float* __restrict__ W2, unsigned short* __restrict__ W2T) {
  int b = blockIdx.x;
  int s = b >> 8, n = b & 255, k = threadIdx.x;
  W2T[((size_t)s * 256 + n) * 256 + k] = f2bf(W2[((size_t)s * 256 + k) * 256 + n]);
}

// ============================ merged select kernel ============================
struct SelDesc {
  const float* qptr[7];
  const float* pptr[7];
  int pbase[7];
  int soff[7];
  int w1off[7];
  int b1off[7];
  int foff[7];
  int blkstart[8];
};

__global__ __launch_bounds__(256) void bq_select_grid(
    SelDesc d, const float* __restrict__ W1all, const float* __restrict__ b1all,
    const float4* __restrict__ binned, const int* __restrict__ starts,
    unsigned short* __restrict__ fbuf) {
  __shared__ unsigned long long keys[4][CAND_CAP];
  __shared__ unsigned long long tmpb[4][2][TMP_CAP];
  __shared__ unsigned long long Tkey[4][2];
  __shared__ int hist32[4][256];
  __shared__ int hist16[4][64];
  __shared__ int bbin[4][2];
  __shared__ int msel[4][2];
  __shared__ float4 sel[4][32];
  __shared__ int rowstart[4][28];
  __shared__ int rowadj[4][28];

  const int tid = threadIdx.x, lane = tid & 63, wv = tid >> 6;

  int st = 0;
  while ((int)blockIdx.x >= d.blkstart[st + 1]) ++st;
  const int qlocal = ((int)blockIdx.x - d.blkstart[st]) * 4 + wv;
  const float* qpts = d.qptr[st];
  const float* ppts = d.pptr[st];
  const int pbase = d.pbase[st];
  const int soff = d.soff[st];

#pragma unroll
  for (int i = 0; i < 4; ++i) hist32[wv][lane + 64 * i] = 0;
  hist16[wv][lane] = 0;
  if (lane == 0) {
    Tkey[wv][0] = 0; Tkey[wv][1] = 0;
    bbin[wv][0] = -1; bbin[wv][1] = -1;
    msel[wv][0] = 0; msel[wv][1] = 0;
  }
  const float qx = qpts[qlocal * 3 + 0];
  const float qy = qpts[qlocal * 3 + 1];
  const float qz = qpts[qlocal * 3 + 2];

  // ---- build flattened row table (cull rows, prefix-scan lengths) ----
  const int cx0 = max(0, (int)floorf((qx - 0.2f) * 10.0f));
  const int cx1 = min(9, (int)floorf((qx + 0.2f) * 10.0f));
  const int cy0 = max(0, (int)floorf((qy - 0.2f) * 10.0f));
  const int cy1 = min(9, (int)floorf((qy + 0.2f) * 10.0f));
  const int cz0 = max(0, (int)floorf((qz - 0.2f) * 10.0f));
  const int cz1 = min(9, (int)floorf((qz + 0.2f) * 10.0f));
  const int ncy = cy1 - cy0 + 1;
  const int nrows = (cz1 - cz0 + 1) * ncy;

  int len = 0, beg = 0;
  if (lane < nrows) {
    int czi = lane / ncy;
    int cz = cz0 + czi;
    int cy = cy0 + (lane - czi * ncy);
    float lo = cz * 0.1f;
    float dz = fmaxf(fmaxf(lo - qz, qz - (lo + 0.1f)), 0.0f);
    float loy = cy * 0.1f;
    float dy = fmaxf(fmaxf(loy - qy, qy - (loy + 0.1f)), 0.0f);
    if (dz * dz + dy * dy <= 0.04f) {
      int row = cz * 100 + cy * 10;
      beg = starts[soff + row + cx0];
      int end = starts[soff + row + cx1 + 1];
      len = end - beg;
    }
  }
  int incl = len;
#pragma unroll
  for (int o = 1; o < 64; o <<= 1) {
    int t = __shfl_up(incl, o, 64);
    if (lane >= o) incl += t;
  }
  const int T = __shfl(incl, 63, 64);
  int excl = incl - len;
  if (lane <= nrows) { rowstart[wv][lane] = excl; rowadj[wv][lane] = beg - excl; }
  __builtin_amdgcn_wave_barrier();
  __threadfence_block();

  // ---- dense scan over flattened candidate stream, ballot compaction ----
  int cnt = 0;
  {
    int r = 0;
    for (int jb = 0; jb < T; jb += 64) {
      int j = jb + lane;
      bool in = j < T;
      float d2 = 1e30f;
      unsigned orig = 0;
      if (in) {
        while (j >= rowstart[wv][r + 1]) ++r;
        int idx = j + rowadj[wv][r];
        float4 P = binned[pbase + idx];
        float dx = P.x - qx, dy = P.y - qy, dz = P.z - qz;
        d2 = dx * dx + dy * dy + dz * dz;
        orig = (unsigned)__float_as_int(P.w);
      }
      bool pred = in && (d2 <= 0.04f);
      unsigned long long mask = __ballot(pred);
      if (pred) {
        int mypos = cnt + __popcll(mask & ((1ull << lane) - 1ull));
        if (mypos < CAND_CAP)
          keys[wv][mypos] = ((unsigned long long)__float_as_uint(d2) << 32) | orig;
        int b = min((int)(d2 * 6400.0f), 255);
        atomicAdd(&hist32[wv][b], 1);
        if (d2 <= 0.01f) atomicAdd(&hist16[wv][min(b, 63)], 1);
      }
      cnt += __popcll(mask);
    }
  }
  __builtin_amdgcn_wave_barrier();
  __threadfence_block();
  const int cntf = min(cnt, CAND_CAP);
  const int k32 = min(32, cntf);

  // ---- hist32 prefix scan (lane owns 4 bins) + k32 boundary bin ----
  {
    int h0 = hist32[wv][lane * 4 + 0];
    int h1 = hist32[wv][lane * 4 + 1];
    int h2 = hist32[wv][lane * 4 + 2];
    int h3 = hist32[wv][lane * 4 + 3];
    int c1 = h0 + h1, c2 = c1 + h2, c3 = c2 + h3;
    int is = c3;
#pragma unroll
    for (int o = 1; o < 64; o <<= 1) {
      int t = __shfl_up(is, o, 64);
      if (lane >= o) is += t;
    }
    int off = is - c3;
    if (k32 > 0) {
      int cum0 = off + h0, cum1 = off + c1, cum2 = off + c2, cum3 = off + c3;
      if (cum0 >= k32 && off  < k32) { bbin[wv][1] = lane * 4 + 0; msel[wv][1] = k32 - off;  }
      if (cum1 >= k32 && cum0 < k32) { bbin[wv][1] = lane * 4 + 1; msel[wv][1] = k32 - cum0; }
      if (cum2 >= k32 && cum1 < k32) { bbin[wv][1] = lane * 4 + 2; msel[wv][1] = k32 - cum1; }
      if (cum3 >= k32 && cum2 < k32) { bbin[wv][1] = lane * 4 + 3; msel[wv][1] = k32 - cum2; }
    }
  }
  // ---- hist16 scan + k16 boundary bin ----
  int k16;
  {
    int gg = hist16[wv][lane];
    int is = gg;
#pragma unroll
    for (int o = 1; o < 64; o <<= 1) {
      int t = __shfl_up(is, o, 64);
      if (lane >= o) is += t;
    }
    int tot = __shfl(is, 63, 64);
    k16 = min(16, tot);
    if (k16 > 0) {
      int prev = is - gg;
      if (is >= k16 && prev < k16) { bbin[wv][0] = lane; msel[wv][0] = k16 - prev; }
    }
  }
  __builtin_amdgcn_wave_barrier();
  __threadfence_block();
  const int b32b = bbin[wv][1];
  const int b16b = bbin[wv][0];

  // ---- collect boundary-bin keys (ballot compaction) ----
  int t32c = 0, t16c = 0;
  for (int base = 0; base < cntf; base += 64) {
    int i = base + lane;
    bool in = i < cntf;
    unsigned long long key = in ? keys[wv][i] : 0xFFFFFFFFFFFFFFFFull;
    float d2 = __uint_as_float((unsigned)(key >> 32));
    int b = min((int)(d2 * 6400.0f), 255);
    bool p1 = in && (b == b32b);
    unsigned long long m1 = __ballot(p1);
    if (p1) {
      int pos = t32c + __popcll(m1 & ((1ull << lane) - 1ull));
      if (pos < TMP_CAP) tmpb[wv][1][pos] = key;
    }
    t32c += __popcll(m1);
    bool p0 = in && (d2 <= 0.01f) && (min(b, 63) == b16b);
    unsigned long long m0 = __ballot(p0);
    if (p0) {
      int pos = t16c + __popcll(m0 & ((1ull << lane) - 1ull));
      if (pos < TMP_CAP) tmpb[wv][0][pos] = key;
    }
    t16c += __popcll(m0);
  }
  __builtin_amdgcn_wave_barrier();
  __threadfence_block();

  // ---- rank-select m-th smallest key in each boundary bin ----
#pragma unroll
  for (int s = 0; s < 2; ++s) {
    const int k = s ? k32 : k16;
    if (k > 0) {
      const int h = min(s ? t32c : t16c, TMP_CAP);
      const int m = msel[wv][s];
      if (lane < h) {
        unsigned long long e = tmpb[wv][s][lane];
        int less = 0;
        for (int j = 0; j < h; ++j) less += (tmpb[wv][s][j] < e) ? 1 : 0;
        if (less == m - 1) Tkey[wv][s] = e;
      }
    }
  }
  __builtin_amdgcn_wave_barrier();
  __threadfence_block();
  const unsigned long long T32 = Tkey[wv][1];
  const unsigned long long T16 = Tkey[wv][0];

  // ---- compact selected neighbors (ballot), rel from raw points ----
  int sc = 0;
  for (int base = 0; base < cntf; base += 64) {
    int i = base + lane;
    bool in = i < cntf;
    unsigned long long key = in ? keys[wv][i] : 0xFFFFFFFFFFFFFFFFull;
    bool pred = in && (k32 > 0) && (key <= T32);
    unsigned long long mask = __ballot(pred);
    if (pred) {
      int pos = sc + __popcll(mask & ((1ull << lane) - 1ull));
      if (pos < 32) {
        int idx = (int)(key & 0xffffffffu);
        float d2 = __uint_as_float((unsigned)(key >> 32));
        float rx = ppts[idx * 3 + 0] - qx;
        float ry = ppts[idx * 3 + 1] - qy;
        float rz = ppts[idx * 3 + 2] - qz;
        bool f16 = (k16 > 0) && (d2 <= 0.01f) && (key <= T16);
        sel[wv][pos] = make_float4(rx, ry, rz, f16 ? 1.0f : 0.0f);
      }
    }
    sc += __popcll(mask);
  }
  __builtin_amdgcn_wave_barrier();
  __threadfence_block();
  const int nsel = min(sc, 32);

  // ---- masked max-pool -> bf16 fbuf row ----
  {
    const float* W1 = W1all + d.w1off[st];
    const float* b1 = b1all + d.b1off[st];
    const int scale = lane >> 5;
    const int hbase = (lane & 31) * 4;
    const float4 wx = *(const float4*)(W1 + scale * 384 + 0 * 128 + hbase);
    const float4 wy = *(const float4*)(W1 + scale * 384 + 1 * 128 + hbase);
    const float4 wz = *(const float4*)(W1 + scale * 384 + 2 * 128 + hbase);
    const float4 bb = *(const float4*)(b1 + scale * 128 + hbase);
    float m0 = -INFINITY, m1 = -INFINITY, m2 = -INFINITY, m3 = -INFINITY;
    for (int n = 0; n < nsel; ++n) {
      float4 e = sel[wv][n];
      bool ok = scale ? true : (e.w > 0.5f);
      float v0 = e.x * wx.x + e.y * wy.x + e.z * wz.x;
      float v1 = e.x * wx.y + e.y * wy.y + e.z * wz.y;
      float v2 = e.x * wx.z + e.y * wy.z + e.z * wz.z;
      float v3 = e.x * wx.w + e.y * wy.w + e.z * wz.w;
      if (ok) { m0 = fmaxf(m0, v0); m1 = fmaxf(m1, v1); m2 = fmaxf(m2, v2); m3 = fmaxf(m3, v3); }
    }
    ushort4 o;
    o.x = f2bf(fmaxf(m0 + bb.x, 0.0f));
    o.y = f2bf(fmaxf(m1 + bb.y, 0.0f));
    o.z = f2bf(fmaxf(m2 + bb.z, 0.0f));
    o.w = f2bf(fmaxf(m3 + bb.w, 0.0f));
    *(ushort4*)(fbuf + (size_t)(d.foff[st] + qlocal) * 256 + lane * 4) = o;
  }
}

// ============================ MFMA GEMM kernel ============================
// out[q] = base[q] + sum_stacks (f_s[q] @ W2_s) + sum b2_s
// Block: 256 threads (4 waves), 32 queries x 256 channels; wave -> 64-channel strip.
struct GemmDesc {
  const float* basep[3];
  float* outp[3];
  int blkstart[4];
  int nst[3];
  int foff[3][3];
  int w2off[3][3];   // ushort offset into W2T
  int b2off[3][3];
};

__global__ __launch_bounds__(256) void bq_gemm_mfma(
    GemmDesc d, const unsigned short* __restrict__ W2T,
    const float* __restrict__ b2all, const unsigned short* __restrict__ fbuf) {
  __shared__ unsigned short ftile[32][264];   // +8 pad keeps 16B align, breaks bank aliasing
  const int tid = threadIdx.x, lane = tid & 63, wv = tid >> 6;

  int rg = 0;
  while ((int)blockIdx.x >= d.blkstart[rg + 1]) ++rg;
  const int qb = ((int)blockIdx.x - d.blkstart[rg]) * 32;

  f32x4 acc[2][4];
#pragma unroll
  for (int mt = 0; mt < 2; ++mt)
#pragma unroll
    for (int nt = 0; nt < 4; ++nt) acc[mt][nt] = (f32x4)0.0f;

  const int nst = d.nst[rg];
  for (int s = 0; s < nst; ++s) {
    __syncthreads();
    {
      const unsigned short* fsrc = fbuf + (size_t)(d.foff[rg][s] + qb) * 256;
#pragma unroll
      for (int i = 0; i < 4; ++i) {
        int c = tid + 256 * i;            // 1024 chunks of 16B
        int row = c >> 5, k8 = (c & 31) * 8;
        *(uint4*)&ftile[row][k8] = *(const uint4*)(fsrc + (size_t)row * 256 + k8);
      }
    }
    __syncthreads();
    const unsigned short* wbase = W2T + d.w2off[rg][s];
#pragma unroll
    for (int kt = 0; kt < 8; ++kt) {
      const int koff = kt * 32 + (lane >> 4) * 8;
      bf16x8 a0 = *(const bf16x8*)&ftile[lane & 15][koff];
      bf16x8 a1 = *(const bf16x8*)&ftile[16 + (lane & 15)][koff];
#pragma unroll
      for (int nt = 0; nt < 4; ++nt) {
        int n = wv * 64 + nt * 16 + (lane & 15);
        bf16x8 bfr = *(const bf16x8*)(wbase + (size_t)n * 256 + koff);
        acc[0][nt] = __builtin_amdgcn_mfma_f32_16x16x32_bf16(a0, bfr, acc[0][nt], 0, 0, 0);
        acc[1][nt] = __builtin_amdgcn_mfma_f32_16x16x32_bf16(a1, bfr, acc[1][nt], 0, 0, 0);
      }
    }
  }

  float bb[4];
#pragma unroll
  for (int nt = 0; nt < 4; ++nt) {
    int c = wv * 64 + nt * 16 + (lane & 15);
    float sum = 0.0f;
    for (int s = 0; s < nst; ++s) sum += b2all[d.b2off[rg][s] + c];
    bb[nt] = sum;
  }

  const float* __restrict__ basep = d.basep[rg];
  float* __restrict__ outp = d.outp[rg];
#pragma unroll
  for (int mt = 0; mt < 2; ++mt) {
#pragma unroll
    for (int r = 0; r < 4; ++r) {
      int q = qb + mt * 16 + (lane >> 4) * 4 + r;
#pragma unroll
      for (int nt = 0; nt < 4; ++nt) {
        int c = wv * 64 + nt * 16 + (lane & 15);
        outp[(size_t)q * 256 + c] = basep[(size_t)q * 256 + c] + acc[mt][nt][r] + bb[nt];
      }
    }
  }
}

// ============================ fused fallback (tiny ws) ============================
__global__ __launch_bounds__(256) void init_out_kernel(
    const float* __restrict__ g, const float* __restrict__ s, const float* __restrict__ v,
    float* __restrict__ out) {
  const int NG = 4096 * 256, NS = 4096 * 256;
  int i = blockIdx.x * 256 + threadIdx.x;
  if (i < NG) out[i] = g[i];
  else if (i < NG + NS) out[i] = s[i - NG];
  else out[i] = v[i - NG - NS];
}

__global__ __launch_bounds__(256) void bq_stack_fused(
    const float* __restrict__ qpts,
    const float* __restrict__ ppts, int Np,
    const float* __restrict__ W1, const float* __restrict__ b1,
    const float* __restrict__ W2, const float* __restrict__ b2,
    float* __restrict__ out) {
  __shared__ unsigned long long keys[M_MAX];
  __shared__ int hist32[256];
  __shared__ int hist16[64];
  __shared__ unsigned long long tmpb[2][FTMP_CAP];
  __shared__ int tmpcnt[2];
  __shared__ float4 sel[32];
  __shared__ int selcnt;
  __shared__ float f_lds[256];
  __shared__ int cnt_s;
  __shared__ unsigned long long T_lds[2];
  __shared__ int bbin[2], msel[2];
  __shared__ int wsum[4];
  __shared__ float qsh[3];

  const int tid = threadIdx.x;
  const int lane = tid & 63;
  const int wv = tid >> 6;
  const int q = blockIdx.x;

  hist32[tid] = 0;
  if (tid < 64) hist16[tid] = 0;
  if (tid == 0) {
    cnt_s = 0; selcnt = 0; tmpcnt[0] = 0; tmpcnt[1] = 0;
    T_lds[0] = ~0ULL; T_lds[1] = ~0ULL;
    qsh[0] = qpts[q * 3 + 0]; qsh[1] = qpts[q * 3 + 1]; qsh[2] = qpts[q * 3 + 2];
  }
  __syncthreads();
  const float qx = qsh[0], qy = qsh[1], qz = qsh[2];

  const float4* pp4 = (const float4*)ppts;
  const int groups = Np >> 2;
  for (int gp = tid; gp < groups; gp += 256) {
    float4 A = pp4[gp * 3 + 0];
    float4 Bv = pp4[gp * 3 + 1];
    float4 C = pp4[gp * 3 + 2];
    float px[4] = {A.x, A.w, Bv.z, C.y};
    float py[4] = {A.y, Bv.x, Bv.w, C.z};
    float pz[4] = {A.z, Bv.y, C.x, C.w};
#pragma unroll
    for (int t = 0; t < 4; ++t) {
      float dx = px[t] - qx, dy = py[t] - qy, dz = pz[t] - qz;
      float d2 = dx * dx + dy * dy + dz * dz;
      if (d2 <= 0.04f) {
        int pos = atomicAdd(&cnt_s, 1);
        if (pos < M_MAX)
          keys[pos] = ((unsigned long long)__float_as_uint(d2) << 32) | (unsigned)(gp * 4 + t);
        int b = min((int)(d2 * 6400.0f), 255);
        atomicAdd(&hist32[b], 1);
        if (d2 <= 0.01f) atomicAdd(&hist16[min(b, 63)], 1);
      }
    }
  }
  __syncthreads();
  const int cnt = min(cnt_s, M_MAX);

  {
    int v = hist32[tid];
#pragma unroll
    for (int o = 1; o < 64; o <<= 1) {
      int t = __shfl_up(v, o, 64);
      if (lane >= o) v += t;
    }
    if (lane == 63) wsum[wv] = v;
    int v16 = 0;
    if (wv == 0) {
      v16 = hist16[lane];
#pragma unroll
      for (int o = 1; o < 64; o <<= 1) {
        int t = __shfl_up(v16, o, 64);
        if (lane >= o) v16 += t;
      }
    }
    __syncthreads();
    int off = 0;
    for (int w = 0; w < wv; ++w) off += wsum[w];
    hist32[tid] = v + off;
    if (wv == 0) hist16[lane] = v16;
    __syncthreads();
  }

  const int k32 = min(32, cnt);
  const int c16tot = hist16[63];
  const int k16 = min(16, c16tot);

  {
    int c = hist32[tid], cp = tid ? hist32[tid - 1] : 0;
    if (k32 > 0 && c >= k32 && cp < k32) { bbin[1] = tid; msel[1] = k32 - cp; }
    if (tid < 64) {
      int c6 = hist16[tid], cp6 = tid ? hist16[tid - 1] : 0;
      if (k16 > 0 && c6 >= k16 && cp6 < k16) { bbin[0] = tid; msel[0] = k16 - cp6; }
    }
  }
  __syncthreads();

  const int b32b = (k32 > 0) ? bbin[1] : -1;
  const int b16b = (k16 > 0) ? bbin[0] : -1;
  for (int i = tid; i < cnt; i += 256) {
    unsigned long long key = keys[i];
    float d2 = __uint_as_float((unsigned)(key >> 32));
    int b = min((int)(d2 * 6400.0f), 255);
    if (b == b32b) { int p = atomicAdd(&tmpcnt[1], 1); if (p < FTMP_CAP) tmpb[1][p] = key; }
    if (d2 <= 0.01f && min(b, 63) == b16b) {
      int p = atomicAdd(&tmpcnt[0], 1); if (p < FTMP_CAP) tmpb[0][p] = key;
    }
  }
  __syncthreads();

  if (wv < 2) {
    const int s = 1 - wv;
    const int k = s ? k32 : k16;
    if (k > 0) {
      const int h = min(tmpcnt[s], FTMP_CAP);
      const int m = msel[s];
      for (int base = 0; base < h; base += 64) {
        int ii = base + lane;
        if (ii < h) {
          unsigned long long e = tmpb[s][ii];
          int less = 0;
          for (int j = 0; j < h; ++j) less += (tmpb[s][j] < e) ? 1 : 0;
          if (less == m - 1) T_lds[s] = e;
        }
      }
    }
  }
  __syncthreads();

  {
    const unsigned long long T32 = (k32 > 0) ? T_lds[1] : 0ULL;
    const unsigned long long T16 = T_lds[0];
    for (int i = tid; i < cnt; i += 256) {
      unsigned long long key = keys[i];
      if (k32 > 0 && key <= T32) {
        float d2 = __uint_as_float((unsigned)(key >> 32));
        int idx = (int)(key & 0xffffffffu);
        float rx = ppts[idx * 3 + 0] - qx;
        float ry = ppts[idx * 3 + 1] - qy;
        float rz = ppts[idx * 3 + 2] - qz;
        bool f16 = (k16 > 0) && (d2 <= 0.01f) && (key <= T16);
        int slot = atomicAdd(&selcnt, 1);
        if (slot < 32) sel[slot] = make_float4(rx, ry, rz, f16 ? 1.0f : 0.0f);
      }
    }
  }
  __syncthreads();

  {
    const int nsel = min(selcnt, 32);
    const int scale = tid >> 7;
    const int h = tid & 127;
    const float w0 = W1[(scale * 3 + 0) * 128 + h];
    const float w1 = W1[(scale * 3 + 1) * 128 + h];
    const float w2 = W1[(scale * 3 + 2) * 128 + h];
    const float bb = b1[scale * 128 + h];
    float maxv = -INFINITY;
    for (int j = 0; j < nsel; ++j) {
      float4 e = sel[j];
      float val = e.x * w0 + e.y * w1 + e.z * w2;
      bool ok = scale ? true : (e.w > 0.5f);
      maxv = ok ? fmaxf(maxv, val) : maxv;
    }
    f_lds[tid] = fmaxf(maxv + bb, 0.0f);
  }
  __syncthreads();

  float* part = (float*)keys;
  {
    float4 acc = make_float4(0.f, 0.f, 0.f, 0.f);
    for (int r = 0; r < 64; ++r) {
      float fv = f_lds[wv * 64 + r];
      float4 w = ((const float4*)W2)[(wv * 64 + r) * 64 + lane];
      acc.x += fv * w.x; acc.y += fv * w.y; acc.z += fv * w.z; acc.w += fv * w.w;
    }
    ((float4*)part)[wv * 64 + lane] = acc;
  }
  __syncthreads();
  {
    float sum = part[0 * 256 + tid] + part[1 * 256 + tid] + part[2 * 256 + tid] +
                part[3 * 256 + tid] + b2[tid];
    out[q * 256 + tid] += sum;
  }
}

// ============================ launch ============================
extern "C" void kernel_launch(void* const* d_in, const int* in_sizes, int n_in,
                              void* d_out, int out_size, void* d_ws, size_t ws_size,
                              hipStream_t stream) {
  const float* g      = (const float*)d_in[0];
  const float* s      = (const float*)d_in[1];
  const float* v      = (const float*)d_in[2];
  const float* geo_t  = (const float*)d_in[3];
  const float* surf_t = (const float*)d_in[4];
  const float* vol_t  = (const float*)d_in[5];
  const float* W1     = (const float*)d_in[6];
  const float* b1     = (const float*)d_in[7];
  const float* W2     = (const float*)d_in[8];
  const float* b2     = (const float*)d_in[9];
  float* out = (float*)d_out;

  const int NG = 4096, NS = 4096, NV = 8192;
  float* out_g = out;
  float* out_s = out + NG * 256;
  float* out_v = out + (NG + NS) * 256;

  const int stackid[7] = {0, 3, 4, 1, 5, 2, 6};
  const float* qp[7]   = {g, g, g, s, s, v, v};
  const int    nq[7]   = {NG, NG, NG, NS, NS, NV, NV};
  const int    pset[7] = {0, 1, 2, 1, 0, 2, 0};
  const float* praw[3] = {g, s, v};
  const int    setbase[3] = {0, 4096, 8192};

  const size_t FB = (size_t)36864 * 256 * sizeof(unsigned short);  // bf16 fbuf
  const size_t WT = (size_t)7 * 256 * 256 * sizeof(unsigned short);
  const size_t GI = (size_t)3 * 1024 * sizeof(int);
  const size_t need = FB + WT + 2 * GI + (size_t)16384 * sizeof(float4);

  if (ws_size >= need) {
    unsigned short* fbuf = (unsigned short*)d_ws;
    unsigned short* W2T  = (unsigned short*)((char*)d_ws + FB);
    int* starts = (int*)((char*)d_ws + FB + WT);
    int* cursor = (int*)((char*)d_ws + FB + WT + GI);
    float4* binned = (float4*)((char*)d_ws + FB + WT + 2 * GI);

    hipMemsetAsync(cursor, 0, GI, stream);
    hipLaunchKernelGGL(grid_count_kernel, dim3(64), dim3(256), 0, stream, g, s, v, cursor);
    hipLaunchKernelGGL(grid_scan_kernel, dim3(3), dim3(1024), 0, stream, cursor, starts);
    hipLaunchKernelGGL(grid_scatter_kernel, dim3(64), dim3(256), 0, stream, g, s, v, cursor, binned);
    hipLaunchKernelGGL(w2_convert_kernel, dim3(7 * 256), dim3(256), 0, stream, W2, W2T);

    SelDesc sd;
    int blk = 0, frow = 0;
    int foffs[7];
    for (int i = 0; i < 7; ++i) {
      sd.qptr[i] = qp[i];
      sd.pptr[i] = praw[pset[i]];
      sd.pbase[i] = setbase[pset[i]];
      sd.soff[i] = pset[i] * 1024;
      sd.w1off[i] = stackid[i] * 768;
      sd.b1off[i] = stackid[i] * 256;
      sd.foff[i] = frow;
      foffs[i] = frow;
      sd.blkstart[i] = blk;
      blk += nq[i] / 4;
      frow += nq[i];
    }
    sd.blkstart[7] = blk;
    hipLaunchKernelGGL(bq_select_grid, dim3(blk), dim3(256), 0, stream,
                       sd, W1, b1, binned, starts, fbuf);

    GemmDesc gd;
    gd.basep[0] = geo_t;  gd.outp[0] = out_g;
    gd.basep[1] = surf_t; gd.outp[1] = out_s;
    gd.basep[2] = vol_t;  gd.outp[2] = out_v;
    gd.blkstart[0] = 0;
    gd.blkstart[1] = NG / 32;
    gd.blkstart[2] = NG / 32 + NS / 32;
    gd.blkstart[3] = NG / 32 + NS / 32 + NV / 32;
    gd.nst[0] = 3; gd.nst[1] = 2; gd.nst[2] = 2;
    const int ridx[3][3] = {{0, 1, 2}, {3, 4, -1}, {5, 6, -1}};
    for (int r = 0; r < 3; ++r)
      for (int t = 0; t < gd.nst[r]; ++t) {
        int i = ridx[r][t];
        gd.foff[r][t] = foffs[i];
        gd.w2off[r][t] = stackid[i] * 256 * 256;
        gd.b2off[r][t] = stackid[i] * 256;
      }
    hipLaunchKernelGGL(bq_gemm_mfma, dim3(gd.blkstart[3]), dim3(256), 0, stream,
                       gd, W2T, b2, fbuf);
  } else {
    const int total = (NG + NS + NV) * 256;
    hipLaunchKernelGGL(init_out_kernel, dim3(total / 256), dim3(256), 0, stream,
                       geo_t, surf_t, vol_t, out);
    auto launch = [&](int stack, const float* qp_, int Nq, const float* pp_, int Np, float* o) {
      hipLaunchKernelGGL(bq_stack_fused, dim3(Nq), dim3(256), 0, stream,
                         qp_, pp_, Np, W1 + stack * 768, b1 + stack * 256,
                         W2 + stack * 256 * 256, b2 + stack * 256, o);
    };
    launch(0, g, NG, g, NG, out_g);
    launch(3, g, NG, s, NS, out_g);
    launch(4, g, NG, v, NV, out_g);
    launch(1, s, NS, s, NS, out_s);
    launch(5, s, NS, g, NG, out_s);
    launch(2, v, NV, v, NV, out_v);
    launch(6, v, NV, g, NG, out_v);
  }
}